// Round 2
// baseline (473.078 us; speedup 1.0000x reference)
//
#include <hip/hip_runtime.h>

typedef _Float16 f16;
typedef f16 f16x2 __attribute__((ext_vector_type(2)));
typedef f16 f16x4 __attribute__((ext_vector_type(4)));
typedef f16 f16x8 __attribute__((ext_vector_type(8)));
typedef float f32x4 __attribute__((ext_vector_type(4)));

#define AS1 __attribute__((address_space(1)))
#define AS3 __attribute__((address_space(3)))

#define NN 8192
#define EE 32768

#if __has_builtin(__builtin_amdgcn_fdot2)
#define HAS_FDOT2 1
#else
#define HAS_FDOT2 0
#endif

__device__ __forceinline__ void glds16(const void* g, void* l) {
  __builtin_amdgcn_global_load_lds((const AS1 unsigned int*)g, (AS3 unsigned int*)l, 16, 0, 0);
}
// cooperative stage, 256 threads, 16B/lane; LDS base passed wave-uniform
__device__ __forceinline__ void stage_bytes(const void* g, void* s, int nbytes, int tid) {
  const int lane = tid & 63;
  for (int off = tid * 16; off < nbytes; off += 4096)
    glds16((const char*)g + off, (char*)s + (off - lane * 16));
}

// ---- P-factorization geometry ----------------------------------------------
// agg[n,i] = sum_{kg<74, j<73} W2p[kg,i,j] * P[n, kg*76+j]
//   P[n, kg*76+j] = sum_{e: tgt=n} ehh[e,kg] * hf[src[e], j]   (kg=73 row: bias, ehh col73=1)
// K = 74*76 = 5624, padded to KTOT=5632 (44 chunks of 128; both P and W2p zero in pads)
#define KTOT 5632

// ---------------- prep: h0 GEMM, ehh, W2p fragment pack, weight casts, segstarts, CSR ----
__global__ void prep_kernel(
    const float* __restrict__ nf, const float* __restrict__ ef,
    const float* __restrict__ W_in, const float* __restrict__ b_in,
    const float* __restrict__ W1, const float* __restrict__ b1,
    const float* __restrict__ W2, const float* __restrict__ b2,
    const float* __restrict__ gWih, const float* __restrict__ gWhh,
    const float* __restrict__ lWih, const float* __restrict__ lWhh,
    const int* __restrict__ batch, const int* __restrict__ Etgt,
    float* __restrict__ h, f16* __restrict__ hf, f16* __restrict__ ehh,
    f16* __restrict__ W2p, f16* __restrict__ WihT, f16* __restrict__ WhhT,
    f16* __restrict__ Wcat, int* __restrict__ segstarts,
    int* __restrict__ count, int* __restrict__ bucket) {
  int t = blockIdx.x * 256 + threadIdx.x;
  if (t < 786432) {                       // h0: [8192][96] fp32+f16, pads zero
    int n = t / 96, i = t - n * 96;
    float v = 0.f;
    if (i < 73) {
      v = b_in[i];
      const float* nr = nf + n * 32;
      #pragma unroll
      for (int f = 0; f < 32; ++f) v += nr[f] * W_in[f * 73 + i];
    }
    h[t] = v; hf[t] = (f16)v;
    return;
  }
  t -= 786432;
  if (t < 2621440) {                      // ehh: [32768][80], col73 = 1.0 (bias), cols 74-79 zero
    int e = t / 80, k = t - e * 80;
    float v;
    if (k < 73) {
      v = b1[k];
      const float* er = ef + e * 16;
      #pragma unroll
      for (int f = 0; f < 16; ++f) v += er[f] * W1[f * 73 + k];
      v = fmaxf(v, 0.f);
    } else v = (k == 73) ? 1.f : 0.f;
    ehh[t] = (f16)v;
    return;
  }
  t -= 2621440;
  if (t < 450560) {                       // W2p: [44 c][4 kstep][5 nt][64 lane][8] fragment order
    int c = t / 10240, r = t - c * 10240;
    int kstep = r / 2560, r2 = r - kstep * 2560;
    int nt = r2 / 512, r3 = r2 - nt * 512;
    int l = r3 >> 3, idx = r3 & 7;
    int mr = l & 15, q = l >> 4;
    int i = nt * 16 + mr;
    int kk = c * 128 + kstep * 32 + q * 8 + idx;   // flat K index
    int kg = kk / 76, j = kk - kg * 76;
    float v = 0.f;
    if (i < 73 && j < 73 && kg < 74)
      v = (kg < 73) ? W2[kg * 5329 + i * 73 + j] : b2[i * 73 + j];
    W2p[t] = (f16)v;
    return;
  }
  t -= 450560;
  if (t < 43008) {                        // WihT/WhhT: [224][96]
    int half = t / 21504, r = t - half * 21504;
    int g = r / 96, k = r - g * 96;
    float v = 0.f;
    if (g < 219 && k < 73) v = half ? gWhh[g * 73 + k] : gWih[g * 73 + k];
    (half ? WhhT : WihT)[r] = (f16)v;
    return;
  }
  t -= 43008;
  if (t < 67744) {                        // Wcat[292][232]: q==hh fold -> [0..72]=wih_q+whh [76..148]=wih_r
    int g = t / 232, k = t - g * 232;
    float v = 0.f;
    if (k < 73) v = lWih[g * 146 + k] + lWhh[g * 73 + k];
    else if (k >= 76 && k < 149) v = lWih[g * 146 + (k - 3)];
    Wcat[t] = (f16)v;
    return;
  }
  t -= 67744;
  if (t < 65) {                           // segstarts: lower_bound(batch, t)
    int key = t, lo = 0, hi = NN;
    while (lo < hi) { int mid = (lo + hi) >> 1; if (batch[mid] < key) lo = mid + 1; else hi = mid; }
    segstarts[t] = lo;
    return;
  }
  t -= 65;
  if (t < EE) {                           // bucket fill: CSR-by-target (cap 64, lambda=4)
    int tg = Etgt[t];
    int slot = atomicAdd(&count[tg], 1);
    if (slot < 64) bucket[tg * 64 + slot] = t;
  }
}

// ---------------- P-build: P[n, kg*76+j] = sum_{e in in(n)} ehh[e,kg]*hf[src,j] ----------
// 2048 blocks x 256 threads; one wave per node. f32 accumulate, f16 store (single rounding).
// 1408 quads/row (22/lane); quads 1406,1407 are K-pad -> zero. Write-BW bound (~92 MB).
__global__ __launch_bounds__(256) void pbuild_kernel(
    const f16* __restrict__ ehh, const f16* __restrict__ hf,
    const int* __restrict__ Esrc, const int* __restrict__ count,
    const int* __restrict__ bucket, f16* __restrict__ P) {
  const int wave = threadIdx.x >> 6, lane = threadIdx.x & 63;
  const int n = blockIdx.x * 4 + wave;
  int cnt = count[n]; if (cnt > 64) cnt = 64;
  const int* bk = bucket + n * 64;
  float acc[22][4];
  #pragma unroll
  for (int qi = 0; qi < 22; ++qi)
    #pragma unroll
    for (int x = 0; x < 4; ++x) acc[qi][x] = 0.f;
  for (int s = 0; s < cnt; ++s) {
    int e = bk[s];                                    // wave-uniform
    const f16* er = ehh + (size_t)e * 80;
    const f16* hr = hf + (size_t)Esrc[e] * 96;        // row is L1/L2-hot (192B, wave-broadcast)
    #pragma unroll
    for (int qi = 0; qi < 22; ++qi) {
      int qd = lane + qi * 64;                        // 0..1407
      if (qd < 1406) {                                // real quads (74*19)
        int kg = qd / 19, jq = qd - kg * 19;
        float ev = (float)er[kg];
        f16x4 hv = *(const f16x4*)(hr + jq * 4);      // j in [0,76): hf cols 73..75 are zero
        acc[qi][0] += ev * (float)hv[0];
        acc[qi][1] += ev * (float)hv[1];
        acc[qi][2] += ev * (float)hv[2];
        acc[qi][3] += ev * (float)hv[3];
      }
    }
  }
  f16* pr = P + (size_t)n * KTOT;
  #pragma unroll
  for (int qi = 0; qi < 22; ++qi) {
    f16x4 v = {(f16)acc[qi][0], (f16)acc[qi][1], (f16)acc[qi][2], (f16)acc[qi][3]};
    *(f16x4*)(pr + (lane + qi * 64) * 4) = v;         // lanes consecutive -> 512B/instr
  }
}

// A-chunk stage: [4 kstep][2 mt][64 lane][8] f16 fragment order via per-lane global addrs
__device__ __forceinline__ void stageA(const f16* __restrict__ P, int n0, int c,
                                       f16* dst, int tid) {
  const int lane = tid & 63;
  #pragma unroll
  for (int p = 0; p < 2; ++p) {
    int off = tid * 16 + p * 4096;
    int slot = off >> 4;
    int kstep = slot >> 7, rem = slot & 127;
    int mt = rem >> 6, l = rem & 63;
    int r = mt * 16 + (l & 15);
    int k = kstep * 32 + ((l >> 4) << 3);
    glds16(P + (size_t)(n0 + r) * KTOT + c * 128 + k, (char*)dst + (off - lane * 16));
  }
}

// ---------------- P-GEMM: agg[n,i] = sum_K P[n,K]*W2p[K,i]; M=8192 N=80 K=5632 -----------
// 256 blocks x 256 thr, BM=32; KC=128/chunk; wave w owns kstep w (K-split), LDS-reduce at end.
// Memory-bound: streams P (92 MB) once; B (901 KB) is L2-resident.
__global__ __launch_bounds__(256, 2) void pgemm_kernel(
    const f16* __restrict__ P, const f16* __restrict__ W2p,
    f16* __restrict__ aggf) {
  __shared__ __align__(16) char smem[57344];
  f16* As = (f16*)smem;                 // 2 x 8192 B
  f16* Bs = (f16*)(smem + 16384);       // 2 x 20480 B
  float* red = (float*)smem;            // 40960 B (epilogue alias, after barrier)
  const int tid = threadIdx.x;
  const int lane = tid & 63, w = tid >> 6;
  const int n0 = blockIdx.x * 32;

  stageA(P, n0, 0, As, tid);
  stage_bytes(W2p, Bs, 20480, tid);

  f32x4 zero = {0.f, 0.f, 0.f, 0.f};
  f32x4 acc[2][5];
  #pragma unroll
  for (int mt = 0; mt < 2; ++mt)
    #pragma unroll
    for (int nt = 0; nt < 5; ++nt) acc[mt][nt] = zero;

  for (int c = 0; c < 44; ++c) {
    __syncthreads();                    // buf[c&1] staged (implicit vmcnt drain)
    if (c + 1 < 44) {
      stageA(P, n0, c + 1, As + ((c + 1) & 1) * 4096, tid);
      stage_bytes((const char*)W2p + (c + 1) * 20480, Bs + ((c + 1) & 1) * 10240, 20480, tid);
    }
    const f16* ab = As + (c & 1) * 4096;
    const f16* bb = Bs + (c & 1) * 10240;
    f16x8 af0 = *(const f16x8*)(ab + (w * 2 + 0) * 512 + lane * 8);  // lane-linear: conflict-free
    f16x8 af1 = *(const f16x8*)(ab + (w * 2 + 1) * 512 + lane * 8);
    #pragma unroll
    for (int nt = 0; nt < 5; ++nt) {
      f16x8 bf = *(const f16x8*)(bb + (w * 5 + nt) * 512 + lane * 8);
      acc[0][nt] = __builtin_amdgcn_mfma_f32_16x16x32_f16(af0, bf, acc[0][nt], 0, 0, 0);
      acc[1][nt] = __builtin_amdgcn_mfma_f32_16x16x32_f16(af1, bf, acc[1][nt], 0, 0, 0);
    }
  }
  // cross-wave K-reduction; C layout col=lane&15, row=(lane>>4)*4+reg
  __syncthreads();
  const int q = lane >> 4, mr = lane & 15;
  #pragma unroll
  for (int mt = 0; mt < 2; ++mt)
    #pragma unroll
    for (int nt = 0; nt < 5; ++nt)
      #pragma unroll
      for (int reg = 0; reg < 4; ++reg)
        red[(w * 32 + mt * 16 + q * 4 + reg) * 80 + nt * 16 + mr] = acc[mt][nt][reg];
  __syncthreads();
  for (int idx = tid; idx < 3072; idx += 256) {
    int row = idx / 96, i = idx - row * 96;
    float s = 0.f;
    if (i < 80) {
      #pragma unroll
      for (int ww = 0; ww < 4; ++ww) s += red[(ww * 32 + row) * 80 + i];
    }
    aggf[(size_t)(n0 + row) * 96 + i] = (f16)s;   // cols 80..95 zeroed
  }
}

// ---------------- GRU gates GEMMs: G[0]=agg@WihT, G[1]=h@WhhT (G stored f16) ----------------
__global__ __launch_bounds__(256, 1) void grugemm_kernel(
    const f16* __restrict__ aggf, const f16* __restrict__ hf,
    const f16* __restrict__ WihT, const f16* __restrict__ WhhT,
    f16* __restrict__ G) {
  __shared__ __align__(16) f16 As[128 * 96];
  __shared__ __align__(16) f16 Bs[224 * 96];
  const int tid = threadIdx.x;
  const int bz = blockIdx.x >> 6, bm = blockIdx.x & 63;
  const int m0 = bm * 128;
  const f16* A = bz ? hf : aggf;
  const f16* B = bz ? WhhT : WihT;
  f16* out = G + bz * (NN * 224);
  stage_bytes(A + m0 * 96, As, 128 * 96 * 2, tid);
  stage_bytes(B, Bs, 224 * 96 * 2, tid);
  const int wave = tid >> 6, lane = tid & 63, q = lane >> 4, mr = lane & 15;
  __syncthreads();
  f16x8 af[2][3];
  #pragma unroll
  for (int mt = 0; mt < 2; ++mt)
    #pragma unroll
    for (int ks = 0; ks < 3; ++ks)
      af[mt][ks] = *(const f16x8*)(As + (wave * 32 + mt * 16 + mr) * 96 + ks * 32 + q * 8);
  f32x4 zero = {0.f, 0.f, 0.f, 0.f};
  f32x4 acc[2][14];
  #pragma unroll
  for (int mt = 0; mt < 2; ++mt)
    #pragma unroll
    for (int nt = 0; nt < 14; ++nt) acc[mt][nt] = zero;
  #pragma unroll
  for (int nt = 0; nt < 14; ++nt) {
    #pragma unroll
    for (int ks = 0; ks < 3; ++ks) {
      f16x8 bf = *(const f16x8*)(Bs + (nt * 16 + mr) * 96 + ks * 32 + q * 8);
      #pragma unroll
      for (int mt = 0; mt < 2; ++mt)
        acc[mt][nt] = __builtin_amdgcn_mfma_f32_16x16x32_f16(af[mt][ks], bf, acc[mt][nt], 0, 0, 0);
    }
  }
  #pragma unroll
  for (int mt = 0; mt < 2; ++mt)
    #pragma unroll
    for (int reg = 0; reg < 4; ++reg) {
      int row = m0 + wave * 32 + mt * 16 + q * 4 + reg;
      #pragma unroll
      for (int nt = 0; nt < 14; ++nt)
        out[row * 224 + nt * 16 + mr] = (f16)acc[mt][nt][reg];
    }
}

// ---------------- GRU elementwise update (G in f16) ----------------
__global__ void gate_kernel(const f16* __restrict__ G, const float* __restrict__ bih,
                            const float* __restrict__ bhh, float* __restrict__ h,
                            f16* __restrict__ hf) {
  int idx = blockIdx.x * 256 + threadIdx.x;  // exactly 8192*73
  int n = idx / 73, i = idx - n * 73;
  const f16* g0 = G + n * 224;
  const f16* g1 = G + NN * 224 + n * 224;
  float rr = (float)g0[i] + bih[i] + (float)g1[i] + bhh[i];
  rr = 1.f / (1.f + __expf(-rr));
  float zz = (float)g0[73 + i] + bih[73 + i] + (float)g1[73 + i] + bhh[73 + i];
  zz = 1.f / (1.f + __expf(-zz));
  float nx = (float)g0[146 + i] + bih[146 + i] + rr * ((float)g1[146 + i] + bhh[146 + i]);
  float nn_ = 2.f / (1.f + __expf(-2.f * nx)) - 1.f;
  float hv = h[n * 96 + i];
  float hn = (1.f - zz) * nn_ + zz * hv;
  h[n * 96 + i] = hn;
  hf[n * 96 + i] = (f16)hn;
}

// ---------------- Set2Set helpers ----------------
__device__ __forceinline__ float wred_sum(float v) {
  #pragma unroll
  for (int off = 32; off; off >>= 1) v += __shfl_xor(v, off, 64);
  return v;
}
// fp32-accumulating f16 dots (v_dot2_f32_f16)
__device__ __forceinline__ float dot8(f16x8 w, f16x8 x, float acc) {
#if HAS_FDOT2
  acc = __builtin_amdgcn_fdot2((f16x2)__builtin_shufflevector(w, w, 0, 1),
                               (f16x2)__builtin_shufflevector(x, x, 0, 1), acc, false);
  acc = __builtin_amdgcn_fdot2((f16x2)__builtin_shufflevector(w, w, 2, 3),
                               (f16x2)__builtin_shufflevector(x, x, 2, 3), acc, false);
  acc = __builtin_amdgcn_fdot2((f16x2)__builtin_shufflevector(w, w, 4, 5),
                               (f16x2)__builtin_shufflevector(x, x, 4, 5), acc, false);
  acc = __builtin_amdgcn_fdot2((f16x2)__builtin_shufflevector(w, w, 6, 7),
                               (f16x2)__builtin_shufflevector(x, x, 6, 7), acc, false);
#else
  #pragma unroll
  for (int e = 0; e < 8; ++e) acc += (float)w[e] * (float)x[e];
#endif
  return acc;
}
__device__ __forceinline__ float dot4(f16x4 w, f16x4 x, float acc) {
#if HAS_FDOT2
  acc = __builtin_amdgcn_fdot2((f16x2)__builtin_shufflevector(w, w, 0, 1),
                               (f16x2)__builtin_shufflevector(x, x, 0, 1), acc, false);
  acc = __builtin_amdgcn_fdot2((f16x2)__builtin_shufflevector(w, w, 2, 3),
                               (f16x2)__builtin_shufflevector(x, x, 2, 3), acc, false);
#else
  #pragma unroll
  for (int e = 0; e < 4; ++e) acc += (float)w[e] * (float)x[e];
#endif
  return acc;
}

#define S2SCAP 256   // absolute per-segment cap (binomial mean 128, sd 11)
#define NCAP 190     // rows cached in LDS; [NCAP,segT) via global fallback (normally empty)

// ---------------- Set2Set v8: folded LSTM weights (q==hh -> K=146), unguarded P4 ----------
__global__ __launch_bounds__(512, 2) void s2s_kernel(
    const float* __restrict__ h, const f16* __restrict__ hf,
    const f16* __restrict__ Wcat,
    const float* __restrict__ lbih, const float* __restrict__ lbhh,
    const float* __restrict__ Wout, const float* __restrict__ bout,
    const int* __restrict__ segstarts, float* __restrict__ out) {
  __shared__ __align__(16) f16 hseg[NCAP * 84];   // 31920 B, row stride 84 f16 (b64-aligned)
  __shared__ __align__(16) f16 xcat[240];
  __shared__ float hhv[80];
  __shared__ float gatesv[292];
  __shared__ float earr[S2SCAP];
  __shared__ float red[4];
  __shared__ __align__(16) float rpart[19 * 80];
  const int t = threadIdx.x, b = blockIdx.x;
  const int wid = t >> 6, lane = t & 63;

  const int s0 = segstarts[b];
  int segT = segstarts[b + 1] - s0;
  if (segT > S2SCAP) segT = S2SCAP;
  const int c = segT < NCAP ? segT : NCAP;

  if (t < 240) xcat[t] = (f16)0.f;
  if (t < 80) hhv[t] = 0.f;
  if (t < S2SCAP) earr[t] = 0.f;   // pre-zero so P4 runs unguarded

  // stage hseg rows (f16, cols 0..75 data incl. zero pads 73..75; cols 76..83 zeroed);
  // rows [c, NCAP) fully zeroed so P4 needs no per-row guard (0*0 contributions)
  for (int r = wid; r < NCAP; r += 8) {
    if (lane < 21) {
      f16x4 v = {(f16)0.f, (f16)0.f, (f16)0.f, (f16)0.f};
      if (r < c && lane < 19)
        v = *(const f16x4*)(hf + (size_t)(s0 + r) * 96 + lane * 4);
      *(f16x4*)(hseg + r * 84 + lane * 4) = v;
    }
  }

  const bool isg = (t >= 220);
  const int g2 = t - 220;
  float bias = 0.f;
  if (isg) bias = lbih[g2] + lbhh[g2];
  // Folded LSTM weight row RESIDENT in registers (q==hh: Wcat[0..72]=wih_q+whh, [76..148]=wih_r)
  f16x8 wihF[19];
  {
    const f16* wr = Wcat + (size_t)(isg ? g2 : 0) * 232;
    #pragma unroll
    for (int v = 0; v < 19; ++v) wihF[v] = *(const f16x8*)(wr + v * 8);
  }
  const int nc = t / 10, fo = t - nc * 10;    // readout mapping (t<190)
  float creg = 0.f;                            // LSTM cell state (t<73)
  __syncthreads();

  for (int iter = 0; iter < 12; ++iter) {
    // ---- P1: LSTM gate matvec (292 threads), folded K=152, 4 accumulators ----
    if (isg) {
      float a0 = bias, a1 = 0.f, a2 = 0.f, a3 = 0.f;
      #pragma unroll
      for (int v = 0; v < 19; ++v) {
        f16x8 x = *(const f16x8*)(xcat + v * 8);
        int sel = v & 3;
        if (sel == 0) a0 = dot8(wihF[v], x, a0);
        else if (sel == 1) a1 = dot8(wihF[v], x, a1);
        else if (sel == 2) a2 = dot8(wihF[v], x, a2);
        else a3 = dot8(wihF[v], x, a3);
      }
      gatesv[g2] = (a0 + a1) + (a2 + a3);
    }
    __syncthreads();
    // ---- P2: LSTM elementwise update (t<73) ----
    if (t < 73) {
      float ig = 1.f / (1.f + __expf(-gatesv[t]));
      float fg = 1.f / (1.f + __expf(-gatesv[73 + t]));
      float gx = gatesv[146 + t];
      float gg = 2.f / (1.f + __expf(-2.f * gx)) - 1.f;
      float og = 1.f / (1.f + __expf(-gatesv[219 + t]));
      creg = fg * creg + ig * gg;
      float cth = 2.f / (1.f + __expf(-2.f * creg)) - 1.f;
      float hh = og * cth;
      hhv[t] = hh;
      xcat[t] = (f16)hh;        // q slot (doubles as hh via folded weights)
    }
    __syncthreads();
    // ---- P3: logits + exp + per-wave sums (t<192, node per thread, f16 dot) ----
    if (wid < 3) {
      float a = 0.f;
      if (t < c) {
        const f16* hp = hseg + t * 84;
        float e0 = 0.f, e1 = 0.f;
        #pragma unroll
        for (int k = 0; k < 9; ++k) {
          f16x4 h0 = *(const f16x4*)(hp + 8 * k);
          f16x4 h1 = *(const f16x4*)(hp + 8 * k + 4);
          f16x4 x0 = *(const f16x4*)(xcat + 8 * k);
          f16x4 x1 = *(const f16x4*)(xcat + 8 * k + 4);
          e0 = dot4(h0, x0, e0);
          e1 = dot4(h1, x1, e1);
        }
        f16x4 ht = *(const f16x4*)(hp + 72);
        f16x4 xt = *(const f16x4*)(xcat + 72);
        e0 = dot4(ht, xt, e0);
        a = __expf(fminf(e0 + e1, 80.f));  // logits bounded; no max-sub in fp32
        earr[t] = a;
      }
      float ws = wred_sum(a);
      if (lane == 0) red[wid] = ws;
    }
    // fallback logits for nodes >= NCAP (normally zero-trip)
    if (wid == 0) {
      float fa = 0.f;
      int n = NCAP + lane;
      if (n < segT) {
        const float* hr = h + (size_t)(s0 + n) * 96;
        float e = 0.f;
        for (int i = 0; i < 73; ++i) e += hr[i] * hhv[i];
        fa = __expf(fminf(e, 80.f));
        earr[n] = fa;
      }
      float ws2 = wred_sum(fa);
      if (lane == 0) red[3] = ws2;
    }
    __syncthreads();
    // ---- P4: weighted readout partials (unguarded: earr/hseg zero-padded) ----
    if (t < 190) {
      float r0 = 0.f, r1 = 0.f, r2 = 0.f, r3 = 0.f, r4 = 0.f, r5 = 0.f, r6 = 0.f, r7 = 0.f;
      #pragma unroll
      for (int j = 0; j < 10; ++j) {
        int n = nc * 10 + j;
        float a = earr[n];
        const f16* hp = hseg + n * 84 + fo * 8;
        f16x4 v0 = *(const f16x4*)(hp);
        f16x4 v1 = *(const f16x4*)(hp + 4);
        r0 += a * (float)v0[0]; r1 += a * (float)v0[1];
        r2 += a * (float)v0[2]; r3 += a * (float)v0[3];
        r4 += a * (float)v1[0]; r5 += a * (float)v1[1];
        r6 += a * (float)v1[2]; r7 += a * (float)v1[3];
      }
      if (nc == 18) {  // fallback nodes from global hf (normally zero-trip)
        for (int n = NCAP; n < segT; ++n) {
          float a = earr[n];
          const f16* hp = hf + (size_t)(s0 + n) * 96 + fo * 8;
          f16x4 v0 = *(const f16x4*)(hp);
          f16x4 v1 = *(const f16x4*)(hp + 4);
          r0 += a * (float)v0[0]; r1 += a * (float)v0[1];
          r2 += a * (float)v0[2]; r3 += a * (float)v0[3];
          r4 += a * (float)v1[0]; r5 += a * (float)v1[1];
          r6 += a * (float)v1[2]; r7 += a * (float)v1[3];
        }
      }
      f32x4 wa = {r0, r1, r2, r3}, wb = {r4, r5, r6, r7};
      *(f32x4*)(rpart + nc * 80 + fo * 8) = wa;
      *(f32x4*)(rpart + nc * 80 + fo * 8 + 4) = wb;
    }
    __syncthreads();
    // ---- P5: combine partials -> r into xcat (t<80) ----
    if (t < 80) {
      float S = red[0] + red[1] + red[2] + red[3];
      float invS = (S > 0.f) ? (1.f / S) : 0.f;
      float r = 0.f;
      #pragma unroll
      for (int ch = 0; ch < 19; ++ch) r += rpart[ch * 80 + t];
      if (t < 73) xcat[76 + t] = (f16)(r * invS);
    }
    __syncthreads();
  }
  // ---- output: out[b] = bout + hh . Wout ----
  if (t < 80) gatesv[t] = (t < 73) ? hhv[t] * Wout[t] : 0.f;
  __syncthreads();
  if (t == 0) {
    float a = bout[0];
    for (int i = 0; i < 73; ++i) a += gatesv[i];
    out[b] = a;
  }
}

// ---------------- workspace layout (bytes; ws_size = 256 MiB per harness fill) ----------------
#define OFF_H      0u          // float [8192][96]
#define OFF_G      3145728u    // f16 [2][8192][224] gate pre-activations
#define OFF_HF     17825792u   // f16 [8192][96]
#define OFF_AGGF   19398656u   // f16 [8192][96]
#define OFF_EHH    20971520u   // f16 [32768][80]
#define OFF_W2P    26214400u   // f16 [44][10240] fragment order (901 KB)
#define OFF_WIHT   27443200u   // f16 [224][96]
#define OFF_WHHT   27486208u   // f16 [224][96]
#define OFF_WCAT   27529216u   // f16 [292][232]
#define OFF_SEG    27664704u   // int [65]
#define OFF_CNT    27665024u   // int [8192]
#define OFF_BKT    27697792u   // int [8192][64]
#define OFF_P      29794944u   // f16 [8192][5632] outer-product aggregate (92.3 MB, end ~122 MB)

extern "C" void kernel_launch(void* const* d_in, const int* in_sizes, int n_in,
                              void* d_out, int out_size, void* d_ws, size_t ws_size,
                              hipStream_t stream) {
  const float* nf   = (const float*)d_in[0];
  const float* ef   = (const float*)d_in[1];
  const float* W_in = (const float*)d_in[2];
  const float* b_in = (const float*)d_in[3];
  const float* W1   = (const float*)d_in[4];
  const float* b1   = (const float*)d_in[5];
  const float* W2   = (const float*)d_in[6];
  const float* b2   = (const float*)d_in[7];
  const float* gWih = (const float*)d_in[8];
  const float* gWhh = (const float*)d_in[9];
  const float* gbih = (const float*)d_in[10];
  const float* gbhh = (const float*)d_in[11];
  const float* lWih = (const float*)d_in[12];
  const float* lWhh = (const float*)d_in[13];
  const float* lbih = (const float*)d_in[14];
  const float* lbhh = (const float*)d_in[15];
  const float* Wout = (const float*)d_in[16];
  const float* bout = (const float*)d_in[17];
  const int* Esrc   = (const int*)d_in[18];
  const int* Etgt   = (const int*)d_in[19];
  const int* batch  = (const int*)d_in[20];

  char* ws = (char*)d_ws;
  float* h    = (float*)(ws + OFF_H);
  f16* G      = (f16*)(ws + OFF_G);
  f16* P      = (f16*)(ws + OFF_P);
  f16* hf     = (f16*)(ws + OFF_HF);
  f16* aggf   = (f16*)(ws + OFF_AGGF);
  f16* ehh    = (f16*)(ws + OFF_EHH);
  f16* W2p    = (f16*)(ws + OFF_W2P);
  f16* WihT   = (f16*)(ws + OFF_WIHT);
  f16* WhhT   = (f16*)(ws + OFF_WHHT);
  f16* Wcat   = (f16*)(ws + OFF_WCAT);
  int* segst  = (int*)(ws + OFF_SEG);
  int* cnt    = (int*)(ws + OFF_CNT);
  int* bkt    = (int*)(ws + OFF_BKT);

  hipMemsetAsync(cnt, 0, NN * sizeof(int), stream);
  prep_kernel<<<15634, 256, 0, stream>>>(nf, ef, W_in, b_in, W1, b1, W2, b2,
                                         gWih, gWhh, lWih, lWhh, batch, Etgt,
                                         h, hf, ehh, W2p, WihT, WhhT, Wcat,
                                         segst, cnt, bkt);
  for (int step = 0; step < 3; ++step) {
    pbuild_kernel<<<2048, 256, 0, stream>>>(ehh, hf, Esrc, cnt, bkt, P);
    pgemm_kernel<<<256, 256, 0, stream>>>(P, W2p, aggf);
    grugemm_kernel<<<128, 256, 0, stream>>>(aggf, hf, WihT, WhhT, G);
    gate_kernel<<<2336, 256, 0, stream>>>(G, gbih, gbhh, h, hf);
  }
  s2s_kernel<<<64, 512, 0, stream>>>(h, hf, Wcat, lbih, lbhh, Wout, bout, segst,
                                     (float*)d_out);
}

// Round 3
// 374.411 us; speedup vs baseline: 1.2635x; 1.2635x over previous
//
#include <hip/hip_runtime.h>

typedef _Float16 f16;
typedef f16 f16x2 __attribute__((ext_vector_type(2)));
typedef f16 f16x4 __attribute__((ext_vector_type(4)));
typedef f16 f16x8 __attribute__((ext_vector_type(8)));
typedef float f32x4 __attribute__((ext_vector_type(4)));

#define AS1 __attribute__((address_space(1)))
#define AS3 __attribute__((address_space(3)))

#define NN 8192
#define EE 32768

#if __has_builtin(__builtin_amdgcn_fdot2)
#define HAS_FDOT2 1
#else
#define HAS_FDOT2 0
#endif

__device__ __forceinline__ void glds16(const void* g, void* l) {
  __builtin_amdgcn_global_load_lds((const AS1 unsigned int*)g, (AS3 unsigned int*)l, 16, 0, 0);
}
// cooperative stage, 256 threads, 16B/lane; LDS base passed wave-uniform
__device__ __forceinline__ void stage_bytes(const void* g, void* s, int nbytes, int tid) {
  const int lane = tid & 63;
  for (int off = tid * 16; off < nbytes; off += 4096)
    glds16((const char*)g + off, (char*)s + (off - lane * 16));
}

// ---------------- prep: h0 GEMM, ehh, W2 fragment repack (80 kg), weight casts, segstarts, CSR ----
__global__ void prep_kernel(
    const float* __restrict__ nf, const float* __restrict__ ef,
    const float* __restrict__ W_in, const float* __restrict__ b_in,
    const float* __restrict__ W1, const float* __restrict__ b1,
    const float* __restrict__ W2, const float* __restrict__ b2,
    const float* __restrict__ gWih, const float* __restrict__ gWhh,
    const float* __restrict__ lWih, const float* __restrict__ lWhh,
    const int* __restrict__ batch, const int* __restrict__ Etgt,
    float* __restrict__ h, f16* __restrict__ hf, f16* __restrict__ ehh,
    f16* __restrict__ W2f, f16* __restrict__ WihT, f16* __restrict__ WhhT,
    f16* __restrict__ Wcat, int* __restrict__ segstarts,
    int* __restrict__ count, int* __restrict__ bucket) {
  int t = blockIdx.x * 256 + threadIdx.x;
  if (t < 786432) {                       // h0: [8192][96] fp32+f16, pads zero
    int n = t / 96, i = t - n * 96;
    float v = 0.f;
    if (i < 73) {
      v = b_in[i];
      const float* nr = nf + n * 32;
      #pragma unroll
      for (int f = 0; f < 32; ++f) v += nr[f] * W_in[f * 73 + i];
    }
    h[t] = v; hf[t] = (f16)v;
    return;
  }
  t -= 786432;
  if (t < 2621440) {                      // ehh: [32768][80], col73 = 1.0 (bias), cols 74-79 zero
    int e = t / 80, k = t - e * 80;
    float v;
    if (k < 73) {
      v = b1[k];
      const float* er = ef + e * 16;
      #pragma unroll
      for (int f = 0; f < 16; ++f) v += er[f] * W1[f * 73 + k];
      v = fmaxf(v, 0.f);
    } else v = (k == 73) ? 1.f : 0.f;
    ehh[t] = (f16)v;
    return;
  }
  t -= 2621440;
  if (t < 614400) {                       // W2f: [80 kg][5 nt][3 ks][64 lane][8]; kg>=74 zero
    int kg = t / 7680, r = t - kg * 7680;
    int nt = r / 1536, r2 = r - nt * 1536;
    int ks = r2 / 512, r3 = r2 - ks * 512;
    int l = r3 >> 3, j = r3 & 7;
    int mr = l & 15, q = l >> 4;
    int i = nt * 16 + mr, jj = ks * 32 + q * 8 + j;
    float v = 0.f;
    if (i < 73 && jj < 73) {
      if (kg < 73) v = W2[kg * 5329 + i * 73 + jj];
      else if (kg == 73) v = b2[i * 73 + jj];
    }
    W2f[t] = (f16)v;
    return;
  }
  t -= 614400;
  if (t < 43008) {                        // WihT/WhhT: [224][96]
    int half = t / 21504, r = t - half * 21504;
    int g = r / 96, k = r - g * 96;
    float v = 0.f;
    if (g < 219 && k < 73) v = half ? gWhh[g * 73 + k] : gWih[g * 73 + k];
    (half ? WhhT : WihT)[r] = (f16)v;
    return;
  }
  t -= 43008;
  if (t < 67744) {                        // Wcat[292][232]: q==hh fold -> [0..72]=wih_q+whh [76..148]=wih_r
    int g = t / 232, k = t - g * 232;
    float v = 0.f;
    if (k < 73) v = lWih[g * 146 + k] + lWhh[g * 73 + k];
    else if (k >= 76 && k < 149) v = lWih[g * 146 + (k - 3)];
    Wcat[t] = (f16)v;
    return;
  }
  t -= 67744;
  if (t < 65) {                           // segstarts: lower_bound(batch, t)
    int key = t, lo = 0, hi = NN;
    while (lo < hi) { int mid = (lo + hi) >> 1; if (batch[mid] < key) lo = mid + 1; else hi = mid; }
    segstarts[t] = lo;
    return;
  }
  t -= 65;
  if (t < EE) {                           // bucket fill: CSR-by-target (cap 64, lambda=4)
    int tg = Etgt[t];
    int slot = atomicAdd(&count[tg], 1);
    if (slot < 64) bucket[tg * 64 + slot] = t;
  }
}

// ---------------- edge-network matvec: m[e,i] = sum_{kg,j} ehh[e,kg] * hf[src[e],j] * W2[kg][i][j] ----
// 512 blocks x 256 threads: bm (128) x ksp (4). Block owns 256 edges (4 m-tiles/wave, 4 waves)
// over K-quarter kg[ksp*20,(ksp+1)*20). Quarters write DISJOINT f16 ranges m[e][ksp*80+i]
// (single writer, no atomics). Chunk = 2 kg -> LDS 61.4KB -> 2 blocks/CU (2 waves/SIMD).
__global__ __launch_bounds__(256, 2) void vgemm_kernel(
    const f16* __restrict__ ehh, const f16* __restrict__ hf,
    const f16* __restrict__ W2f, const int* __restrict__ Esrc,
    f16* __restrict__ m) {
  __shared__ __align__(16) f16 w2s[2][15360];     // 2 x 30720 B (2-kg chunks, fragment order)
  const int tid = threadIdx.x;
  const int bm = blockIdx.x & 127, ksp = blockIdx.x >> 7;
  const int e0 = bm * 256;
  const int kg0 = ksp * 20;
  const int wave = tid >> 6, lane = tid & 63;
  const int q = lane >> 4, mr = lane & 15;

  stage_bytes(W2f + kg0 * 7680, w2s[0], 30720, tid);

  // hf fragments in registers: wave owns 4 m-tiles (rows e0+wave*64+mt*16+mr)
  f16x8 hsv[4][3];
  size_t er80[4];
  #pragma unroll
  for (int mt = 0; mt < 4; ++mt) {
    int er = e0 + wave * 64 + mt * 16 + mr;
    int srcn = Esrc[er];
    er80[mt] = (size_t)er * 80;
    #pragma unroll
    for (int ks = 0; ks < 3; ++ks)
      hsv[mt][ks] = *(const f16x8*)(hf + (size_t)srcn * 96 + ks * 32 + q * 8);
  }

  f32x4 zero = {0.f, 0.f, 0.f, 0.f};
  f32x4 acc[4][5];
  #pragma unroll
  for (int mt = 0; mt < 4; ++mt)
    #pragma unroll
    for (int nt = 0; nt < 5; ++nt) acc[mt][nt] = zero;

  for (int ch = 0; ch < 10; ++ch) {
    // ev values for this chunk (2 kg): global->reg (L2-hot), issued before the barrier
    f16x2 evq[4];
    #pragma unroll
    for (int mt = 0; mt < 4; ++mt)
      evq[mt] = *(const f16x2*)(ehh + er80[mt] + kg0 + ch * 2);
    __syncthreads();                       // w2s[ch&1] staged
    if (ch + 1 < 10)
      stage_bytes(W2f + (kg0 + (ch + 1) * 2) * 7680, w2s[(ch + 1) & 1], 30720, tid);
    const f16* wb = w2s[ch & 1];
    #pragma unroll
    for (int i = 0; i < 2; ++i) {
      f16x8 af[4][3];
      #pragma unroll
      for (int mt = 0; mt < 4; ++mt) {
        f16 ev = evq[mt][i];
        f16x8 evv = {ev, ev, ev, ev, ev, ev, ev, ev};
        #pragma unroll
        for (int ks = 0; ks < 3; ++ks) af[mt][ks] = hsv[mt][ks] * evv;
      }
      const f16* wbi = wb + i * 7680;
      #pragma unroll
      for (int nt = 0; nt < 5; ++nt) {
        #pragma unroll
        for (int ks = 0; ks < 3; ++ks) {
          f16x8 bf = *(const f16x8*)(wbi + (nt * 3 + ks) * 512 + lane * 8);  // base+lane*16: conflict-free
          #pragma unroll
          for (int mt = 0; mt < 4; ++mt)
            acc[mt][nt] = __builtin_amdgcn_mfma_f32_16x16x32_f16(af[mt][ks], bf, acc[mt][nt], 0, 0, 0);
        }
      }
    }
  }
  // epilogue: C layout col=lane&15, row=(lane>>4)*4+reg; f16 stores to disjoint quarter-row
  #pragma unroll
  for (int mt = 0; mt < 4; ++mt) {
    #pragma unroll
    for (int reg = 0; reg < 4; ++reg) {
      int er = e0 + wave * 64 + mt * 16 + q * 4 + reg;
      f16* mp = m + (size_t)er * 320 + ksp * 80;
      #pragma unroll
      for (int nt = 0; nt < 5; ++nt)
        mp[nt * 16 + mr] = (f16)acc[mt][nt][reg];
    }
  }
}

// ---------------- fused gather + GRU GEMMs + gate: one kernel, row-local (32 nodes/block) ----
// Replaces gather_kernel + grugemm_kernel + gate_kernel: agg and G never touch HBM.
// 256 blocks x 256 thr. LDS: Hs 6K + As 6K + Gs 28.7K = 41K -> 2+ blocks/CU.
__global__ __launch_bounds__(256, 2) void aggru_kernel(
    const f16* __restrict__ m, const int* __restrict__ count,
    const int* __restrict__ bucket, const f16* __restrict__ WihT,
    const f16* __restrict__ WhhT, const float* __restrict__ bih,
    const float* __restrict__ bhh, float* __restrict__ h, f16* __restrict__ hf) {
  __shared__ __align__(16) f16 Hs[32 * 96];     // h-tile (f16), this block's rows
  __shared__ __align__(16) f16 As[32 * 96];     // agg tile (f16), K-pad cols 80..95 zero
  __shared__ __align__(16) f16 Gs[2][32][224];  // gate pre-activations
  const int tid = threadIdx.x;
  const int n0 = blockIdx.x * 32;

  stage_bytes(hf + (size_t)n0 * 96, Hs, 6144, tid);
  {                                             // zero K-pad cols 80..95 of As
    int n = tid >> 3, j = tid & 7;
    f16x2 z = {(f16)0.f, (f16)0.f};
    *(f16x2*)(As + n * 96 + 80 + j * 2) = z;
  }
  // gather: 32x80 outputs, 10 per thread; threads with same n cover consecutive i (coalesced m rows)
  #pragma unroll
  for (int k = 0; k < 10; ++k) {
    int o = tid + k * 256;                      // < 2560
    int n = o / 80, i = o - n * 80;
    int cnt = count[n0 + n]; if (cnt > 64) cnt = 64;
    const int* bk = bucket + (size_t)(n0 + n) * 64;
    float s = 0.f;
    for (int j = 0; j < cnt; ++j) {
      const f16* mp = m + (size_t)bk[j] * 320;
      s += ((float)mp[i] + (float)mp[80 + i]) + ((float)mp[160 + i] + (float)mp[240 + i]);
    }
    As[n * 96 + i] = (f16)s;
  }
  __syncthreads();                              // As/Hs ready (drains glds)
  // GEMM: wave w -> gemm g=w&1 (0:agg@Wih, 1:h@Whh), m-tile mt=w>>1; all 14 nt, K=96
  const int w = tid >> 6, lane = tid & 63, q = lane >> 4, mr = lane & 15;
  const int g = w & 1, mt = w >> 1;
  const f16* Asrc = g ? Hs : As;
  const f16* B = g ? WhhT : WihT;               // B read straight from L2 (86KB/block, 2x reg reuse)
  f16x8 af[3];
  #pragma unroll
  for (int ks = 0; ks < 3; ++ks)
    af[ks] = *(const f16x8*)(Asrc + (mt * 16 + mr) * 96 + ks * 32 + q * 8);
  #pragma unroll
  for (int nt = 0; nt < 14; ++nt) {
    f32x4 acc = {0.f, 0.f, 0.f, 0.f};
    #pragma unroll
    for (int ks = 0; ks < 3; ++ks) {
      f16x8 bf = *(const f16x8*)(B + (nt * 16 + mr) * 96 + ks * 32 + q * 8);
      acc = __builtin_amdgcn_mfma_f32_16x16x32_f16(af[ks], bf, acc, 0, 0, 0);
    }
    #pragma unroll
    for (int reg = 0; reg < 4; ++reg)
      Gs[g][mt * 16 + q * 4 + reg][nt * 16 + mr] = (f16)acc[reg];
  }
  __syncthreads();
  // gate: 32x73 elems, biases from L2
  #pragma unroll
  for (int k = 0; k < 10; ++k) {
    int idx = tid + k * 256;
    if (idx < 2336) {
      int n = idx / 73, i = idx - n * 73;
      float rr = (float)Gs[0][n][i] + bih[i] + (float)Gs[1][n][i] + bhh[i];
      rr = 1.f / (1.f + __expf(-rr));
      float zz = (float)Gs[0][n][73 + i] + bih[73 + i] + (float)Gs[1][n][73 + i] + bhh[73 + i];
      zz = 1.f / (1.f + __expf(-zz));
      float nx = (float)Gs[0][n][146 + i] + bih[146 + i] + rr * ((float)Gs[1][n][146 + i] + bhh[146 + i]);
      float nn_ = 2.f / (1.f + __expf(-2.f * nx)) - 1.f;
      size_t hi_ = (size_t)(n0 + n) * 96 + i;
      float hv = h[hi_];
      float hn = (1.f - zz) * nn_ + zz * hv;
      h[hi_] = hn;
      hf[hi_] = (f16)hn;
    }
  }
}

// ---------------- Set2Set helpers ----------------
__device__ __forceinline__ float wred_sum(float v) {
  #pragma unroll
  for (int off = 32; off; off >>= 1) v += __shfl_xor(v, off, 64);
  return v;
}
// fp32-accumulating f16 dots (v_dot2_f32_f16)
__device__ __forceinline__ float dot8(f16x8 w, f16x8 x, float acc) {
#if HAS_FDOT2
  acc = __builtin_amdgcn_fdot2((f16x2)__builtin_shufflevector(w, w, 0, 1),
                               (f16x2)__builtin_shufflevector(x, x, 0, 1), acc, false);
  acc = __builtin_amdgcn_fdot2((f16x2)__builtin_shufflevector(w, w, 2, 3),
                               (f16x2)__builtin_shufflevector(x, x, 2, 3), acc, false);
  acc = __builtin_amdgcn_fdot2((f16x2)__builtin_shufflevector(w, w, 4, 5),
                               (f16x2)__builtin_shufflevector(x, x, 4, 5), acc, false);
  acc = __builtin_amdgcn_fdot2((f16x2)__builtin_shufflevector(w, w, 6, 7),
                               (f16x2)__builtin_shufflevector(x, x, 6, 7), acc, false);
#else
  #pragma unroll
  for (int e = 0; e < 8; ++e) acc += (float)w[e] * (float)x[e];
#endif
  return acc;
}
__device__ __forceinline__ float dot4(f16x4 w, f16x4 x, float acc) {
#if HAS_FDOT2
  acc = __builtin_amdgcn_fdot2((f16x2)__builtin_shufflevector(w, w, 0, 1),
                               (f16x2)__builtin_shufflevector(x, x, 0, 1), acc, false);
  acc = __builtin_amdgcn_fdot2((f16x2)__builtin_shufflevector(w, w, 2, 3),
                               (f16x2)__builtin_shufflevector(x, x, 2, 3), acc, false);
#else
  #pragma unroll
  for (int e = 0; e < 4; ++e) acc += (float)w[e] * (float)x[e];
#endif
  return acc;
}

#define S2SCAP 256   // absolute per-segment cap (binomial mean 128, sd 11)
#define NCAP 190     // rows cached in LDS; [NCAP,segT) via global fallback (normally empty)

// ---------------- Set2Set v8: folded LSTM weights (q==hh -> K=152), unguarded P4 ----------
__global__ __launch_bounds__(512, 2) void s2s_kernel(
    const float* __restrict__ h, const f16* __restrict__ hf,
    const f16* __restrict__ Wcat,
    const float* __restrict__ lbih, const float* __restrict__ lbhh,
    const float* __restrict__ Wout, const float* __restrict__ bout,
    const int* __restrict__ segstarts, float* __restrict__ out) {
  __shared__ __align__(16) f16 hseg[NCAP * 84];   // 31920 B, row stride 84 f16 (b64-aligned)
  __shared__ __align__(16) f16 xcat[240];
  __shared__ float hhv[80];
  __shared__ float gatesv[292];
  __shared__ float earr[S2SCAP];
  __shared__ float red[4];
  __shared__ __align__(16) float rpart[19 * 80];
  const int t = threadIdx.x, b = blockIdx.x;
  const int wid = t >> 6, lane = t & 63;

  const int s0 = segstarts[b];
  int segT = segstarts[b + 1] - s0;
  if (segT > S2SCAP) segT = S2SCAP;
  const int c = segT < NCAP ? segT : NCAP;

  if (t < 240) xcat[t] = (f16)0.f;
  if (t < 80) hhv[t] = 0.f;
  if (t < S2SCAP) earr[t] = 0.f;   // pre-zero so P4 runs unguarded

  // stage hseg rows (f16, cols 0..75 data incl. zero pads 73..75; cols 76..83 zeroed);
  // rows [c, NCAP) fully zeroed so P4 needs no per-row guard (0*0 contributions)
  for (int r = wid; r < NCAP; r += 8) {
    if (lane < 21) {
      f16x4 v = {(f16)0.f, (f16)0.f, (f16)0.f, (f16)0.f};
      if (r < c && lane < 19)
        v = *(const f16x4*)(hf + (size_t)(s0 + r) * 96 + lane * 4);
      *(f16x4*)(hseg + r * 84 + lane * 4) = v;
    }
  }

  const bool isg = (t >= 220);
  const int g2 = t - 220;
  float bias = 0.f;
  if (isg) bias = lbih[g2] + lbhh[g2];
  // Folded LSTM weight row RESIDENT in registers (q==hh: Wcat[0..72]=wih_q+whh, [76..148]=wih_r)
  f16x8 wihF[19];
  {
    const f16* wr = Wcat + (size_t)(isg ? g2 : 0) * 232;
    #pragma unroll
    for (int v = 0; v < 19; ++v) wihF[v] = *(const f16x8*)(wr + v * 8);
  }
  const int nc = t / 10, fo = t - nc * 10;    // readout mapping (t<190)
  float creg = 0.f;                            // LSTM cell state (t<73)
  __syncthreads();

  for (int iter = 0; iter < 12; ++iter) {
    // ---- P1: LSTM gate matvec (292 threads), folded K=152, 4 accumulators ----
    if (isg) {
      float a0 = bias, a1 = 0.f, a2 = 0.f, a3 = 0.f;
      #pragma unroll
      for (int v = 0; v < 19; ++v) {
        f16x8 x = *(const f16x8*)(xcat + v * 8);
        int sel = v & 3;
        if (sel == 0) a0 = dot8(wihF[v], x, a0);
        else if (sel == 1) a1 = dot8(wihF[v], x, a1);
        else if (sel == 2) a2 = dot8(wihF[v], x, a2);
        else a3 = dot8(wihF[v], x, a3);
      }
      gatesv[g2] = (a0 + a1) + (a2 + a3);
    }
    __syncthreads();
    // ---- P2: LSTM elementwise update (t<73) ----
    if (t < 73) {
      float ig = 1.f / (1.f + __expf(-gatesv[t]));
      float fg = 1.f / (1.f + __expf(-gatesv[73 + t]));
      float gx = gatesv[146 + t];
      float gg = 2.f / (1.f + __expf(-2.f * gx)) - 1.f;
      float og = 1.f / (1.f + __expf(-gatesv[219 + t]));
      creg = fg * creg + ig * gg;
      float cth = 2.f / (1.f + __expf(-2.f * creg)) - 1.f;
      float hh = og * cth;
      hhv[t] = hh;
      xcat[t] = (f16)hh;        // q slot (doubles as hh via folded weights)
    }
    __syncthreads();
    // ---- P3: logits + exp + per-wave sums (t<192, node per thread, f16 dot) ----
    if (wid < 3) {
      float a = 0.f;
      if (t < c) {
        const f16* hp = hseg + t * 84;
        float e0 = 0.f, e1 = 0.f;
        #pragma unroll
        for (int k = 0; k < 9; ++k) {
          f16x4 h0 = *(const f16x4*)(hp + 8 * k);
          f16x4 h1 = *(const f16x4*)(hp + 8 * k + 4);
          f16x4 x0 = *(const f16x4*)(xcat + 8 * k);
          f16x4 x1 = *(const f16x4*)(xcat + 8 * k + 4);
          e0 = dot4(h0, x0, e0);
          e1 = dot4(h1, x1, e1);
        }
        f16x4 ht = *(const f16x4*)(hp + 72);
        f16x4 xt = *(const f16x4*)(xcat + 72);
        e0 = dot4(ht, xt, e0);
        a = __expf(fminf(e0 + e1, 80.f));  // logits bounded; no max-sub in fp32
        earr[t] = a;
      }
      float ws = wred_sum(a);
      if (lane == 0) red[wid] = ws;
    }
    // fallback logits for nodes >= NCAP (normally zero-trip)
    if (wid == 0) {
      float fa = 0.f;
      int n = NCAP + lane;
      if (n < segT) {
        const float* hr = h + (size_t)(s0 + n) * 96;
        float e = 0.f;
        for (int i = 0; i < 73; ++i) e += hr[i] * hhv[i];
        fa = __expf(fminf(e, 80.f));
        earr[n] = fa;
      }
      float ws2 = wred_sum(fa);
      if (lane == 0) red[3] = ws2;
    }
    __syncthreads();
    // ---- P4: weighted readout partials (unguarded: earr/hseg zero-padded) ----
    if (t < 190) {
      float r0 = 0.f, r1 = 0.f, r2 = 0.f, r3 = 0.f, r4 = 0.f, r5 = 0.f, r6 = 0.f, r7 = 0.f;
      #pragma unroll
      for (int j = 0; j < 10; ++j) {
        int n = nc * 10 + j;
        float a = earr[n];
        const f16* hp = hseg + n * 84 + fo * 8;
        f16x4 v0 = *(const f16x4*)(hp);
        f16x4 v1 = *(const f16x4*)(hp + 4);
        r0 += a * (float)v0[0]; r1 += a * (float)v0[1];
        r2 += a * (float)v0[2]; r3 += a * (float)v0[3];
        r4 += a * (float)v1[0]; r5 += a * (float)v1[1];
        r6 += a * (float)v1[2]; r7 += a * (float)v1[3];
      }
      if (nc == 18) {  // fallback nodes from global hf (normally zero-trip)
        for (int n = NCAP; n < segT; ++n) {
          float a = earr[n];
          const f16* hp = hf + (size_t)(s0 + n) * 96 + fo * 8;
          f16x4 v0 = *(const f16x4*)(hp);
          f16x4 v1 = *(const f16x4*)(hp + 4);
          r0 += a * (float)v0[0]; r1 += a * (float)v0[1];
          r2 += a * (float)v0[2]; r3 += a * (float)v0[3];
          r4 += a * (float)v1[0]; r5 += a * (float)v1[1];
          r6 += a * (float)v1[2]; r7 += a * (float)v1[3];
        }
      }
      f32x4 wa = {r0, r1, r2, r3}, wb = {r4, r5, r6, r7};
      *(f32x4*)(rpart + nc * 80 + fo * 8) = wa;
      *(f32x4*)(rpart + nc * 80 + fo * 8 + 4) = wb;
    }
    __syncthreads();
    // ---- P5: combine partials -> r into xcat (t<80) ----
    if (t < 80) {
      float S = red[0] + red[1] + red[2] + red[3];
      float invS = (S > 0.f) ? (1.f / S) : 0.f;
      float r = 0.f;
      #pragma unroll
      for (int ch = 0; ch < 19; ++ch) r += rpart[ch * 80 + t];
      if (t < 73) xcat[76 + t] = (f16)(r * invS);
    }
    __syncthreads();
  }
  // ---- output: out[b] = bout + hh . Wout ----
  if (t < 80) gatesv[t] = (t < 73) ? hhv[t] * Wout[t] : 0.f;
  __syncthreads();
  if (t == 0) {
    float a = bout[0];
    for (int i = 0; i < 73; ++i) a += gatesv[i];
    out[b] = a;
  }
}

// ---------------- workspace layout (bytes; ws_size = 256 MiB per harness fill) ----------------
#define OFF_H      0u          // float [8192][96]
#define OFF_HF     17825792u   // f16 [8192][96]
#define OFF_EHH    20971520u   // f16 [32768][80]
#define OFF_W2F    26214400u   // f16 [80][7680] fragment order
#define OFF_WIHT   27443200u   // f16 [224][96]
#define OFF_WHHT   27486208u   // f16 [224][96]
#define OFF_WCAT   27529216u   // f16 [292][232]
#define OFF_SEG    27664704u   // int [65]
#define OFF_CNT    27665024u   // int [8192]
#define OFF_BKT    27697792u   // int [8192][64]
#define OFF_M      29794944u   // f16 [32768][320] K-quarter partials (end ~50.8 MB)

extern "C" void kernel_launch(void* const* d_in, const int* in_sizes, int n_in,
                              void* d_out, int out_size, void* d_ws, size_t ws_size,
                              hipStream_t stream) {
  const float* nf   = (const float*)d_in[0];
  const float* ef   = (const float*)d_in[1];
  const float* W_in = (const float*)d_in[2];
  const float* b_in = (const float*)d_in[3];
  const float* W1   = (const float*)d_in[4];
  const float* b1   = (const float*)d_in[5];
  const float* W2   = (const float*)d_in[6];
  const float* b2   = (const float*)d_in[7];
  const float* gWih = (const float*)d_in[8];
  const float* gWhh = (const float*)d_in[9];
  const float* gbih = (const float*)d_in[10];
  const float* gbhh = (const float*)d_in[11];
  const float* lWih = (const float*)d_in[12];
  const float* lWhh = (const float*)d_in[13];
  const float* lbih = (const float*)d_in[14];
  const float* lbhh = (const float*)d_in[15];
  const float* Wout = (const float*)d_in[16];
  const float* bout = (const float*)d_in[17];
  const int* Esrc   = (const int*)d_in[18];
  const int* Etgt   = (const int*)d_in[19];
  const int* batch  = (const int*)d_in[20];

  char* ws = (char*)d_ws;
  float* h    = (float*)(ws + OFF_H);
  f16* hf     = (f16*)(ws + OFF_HF);
  f16* ehh    = (f16*)(ws + OFF_EHH);
  f16* W2f    = (f16*)(ws + OFF_W2F);
  f16* WihT   = (f16*)(ws + OFF_WIHT);
  f16* WhhT   = (f16*)(ws + OFF_WHHT);
  f16* Wcat   = (f16*)(ws + OFF_WCAT);
  int* segst  = (int*)(ws + OFF_SEG);
  int* cnt    = (int*)(ws + OFF_CNT);
  int* bkt    = (int*)(ws + OFF_BKT);
  f16* m      = (f16*)(ws + OFF_M);

  hipMemsetAsync(cnt, 0, NN * sizeof(int), stream);
  prep_kernel<<<16273, 256, 0, stream>>>(nf, ef, W_in, b_in, W1, b1, W2, b2,
                                         gWih, gWhh, lWih, lWhh, batch, Etgt,
                                         h, hf, ehh, W2f, WihT, WhhT, Wcat,
                                         segst, cnt, bkt);
  for (int step = 0; step < 3; ++step) {
    vgemm_kernel<<<512, 256, 0, stream>>>(ehh, hf, W2f, Esrc, m);
    aggru_kernel<<<256, 256, 0, stream>>>(m, cnt, bkt, WihT, WhhT, gbih, gbhh, h, hf);
  }
  s2s_kernel<<<64, 512, 0, stream>>>(h, hf, Wcat, lbih, lbhh, Wout, bout, segst,
                                     (float*)d_out);
}

// Round 4
// 345.376 us; speedup vs baseline: 1.3697x; 1.0841x over previous
//
#include <hip/hip_runtime.h>

typedef _Float16 f16;
typedef f16 f16x2 __attribute__((ext_vector_type(2)));
typedef f16 f16x4 __attribute__((ext_vector_type(4)));
typedef f16 f16x8 __attribute__((ext_vector_type(8)));
typedef float f32x4 __attribute__((ext_vector_type(4)));

#define AS1 __attribute__((address_space(1)))
#define AS3 __attribute__((address_space(3)))

#define NN 8192
#define EE 32768

#if __has_builtin(__builtin_amdgcn_fdot2)
#define HAS_FDOT2 1
#else
#define HAS_FDOT2 0
#endif

__device__ __forceinline__ void glds16(const void* g, void* l) {
  __builtin_amdgcn_global_load_lds((const AS1 unsigned int*)g, (AS3 unsigned int*)l, 16, 0, 0);
}
// cooperative stage, 256 threads, 16B/lane; LDS base passed wave-uniform
__device__ __forceinline__ void stage_bytes(const void* g, void* s, int nbytes, int tid) {
  const int lane = tid & 63;
  for (int off = tid * 16; off < nbytes; off += 4096)
    glds16((const char*)g + off, (char*)s + (off - lane * 16));
}

// ---------------- prep: h0 GEMM, ehh, W2 fragment repack (80 kg), weight casts, segstarts, CSR ----
__global__ void prep_kernel(
    const float* __restrict__ nf, const float* __restrict__ ef,
    const float* __restrict__ W_in, const float* __restrict__ b_in,
    const float* __restrict__ W1, const float* __restrict__ b1,
    const float* __restrict__ W2, const float* __restrict__ b2,
    const float* __restrict__ gWih, const float* __restrict__ gWhh,
    const float* __restrict__ lWih, const float* __restrict__ lWhh,
    const int* __restrict__ batch, const int* __restrict__ Etgt,
    float* __restrict__ h, f16* __restrict__ hf, f16* __restrict__ ehh,
    f16* __restrict__ W2f, f16* __restrict__ WihT, f16* __restrict__ WhhT,
    f16* __restrict__ Wcat, int* __restrict__ segstarts,
    int* __restrict__ count, int* __restrict__ bucket) {
  int t = blockIdx.x * 256 + threadIdx.x;
  if (t < 786432) {                       // h0: [8192][96] fp32+f16, pads zero
    int n = t / 96, i = t - n * 96;
    float v = 0.f;
    if (i < 73) {
      v = b_in[i];
      const float* nr = nf + n * 32;
      #pragma unroll
      for (int f = 0; f < 32; ++f) v += nr[f] * W_in[f * 73 + i];
    }
    h[t] = v; hf[t] = (f16)v;
    return;
  }
  t -= 786432;
  if (t < 2621440) {                      // ehh: [32768][80], col73 = 1.0 (bias), cols 74-79 zero
    int e = t / 80, k = t - e * 80;
    float v;
    if (k < 73) {
      v = b1[k];
      const float* er = ef + e * 16;
      #pragma unroll
      for (int f = 0; f < 16; ++f) v += er[f] * W1[f * 73 + k];
      v = fmaxf(v, 0.f);
    } else v = (k == 73) ? 1.f : 0.f;
    ehh[t] = (f16)v;
    return;
  }
  t -= 2621440;
  if (t < 614400) {                       // W2f: [80 kg][5 nt][3 ks][64 lane][8]; kg>=74 zero
    int kg = t / 7680, r = t - kg * 7680;
    int nt = r / 1536, r2 = r - nt * 1536;
    int ks = r2 / 512, r3 = r2 - ks * 512;
    int l = r3 >> 3, j = r3 & 7;
    int mr = l & 15, q = l >> 4;
    int i = nt * 16 + mr, jj = ks * 32 + q * 8 + j;
    float v = 0.f;
    if (i < 73 && jj < 73) {
      if (kg < 73) v = W2[kg * 5329 + i * 73 + jj];
      else if (kg == 73) v = b2[i * 73 + jj];
    }
    W2f[t] = (f16)v;
    return;
  }
  t -= 614400;
  if (t < 43008) {                        // WihT/WhhT: [224][96]
    int half = t / 21504, r = t - half * 21504;
    int g = r / 96, k = r - g * 96;
    float v = 0.f;
    if (g < 219 && k < 73) v = half ? gWhh[g * 73 + k] : gWih[g * 73 + k];
    (half ? WhhT : WihT)[r] = (f16)v;
    return;
  }
  t -= 43008;
  if (t < 67744) {                        // Wcat[292][232]: q==hh fold -> [0..72]=wih_q+whh [76..148]=wih_r
    int g = t / 232, k = t - g * 232;
    float v = 0.f;
    if (k < 73) v = lWih[g * 146 + k] + lWhh[g * 73 + k];
    else if (k >= 76 && k < 149) v = lWih[g * 146 + (k - 3)];
    Wcat[t] = (f16)v;
    return;
  }
  t -= 67744;
  if (t < 65) {                           // segstarts: lower_bound(batch, t)
    int key = t, lo = 0, hi = NN;
    while (lo < hi) { int mid = (lo + hi) >> 1; if (batch[mid] < key) lo = mid + 1; else hi = mid; }
    segstarts[t] = lo;
    return;
  }
  t -= 65;
  if (t < EE) {                           // bucket fill: CSR-by-target (cap 64, lambda=4)
    int tg = Etgt[t];
    int slot = atomicAdd(&count[tg], 1);
    if (slot < 64) bucket[tg * 64 + slot] = t;
  }
}

// ---------------- edge-network matvec: m[e,i] = sum_{kg,j} ehh[e,kg] * hf[src[e],j] * W2[kg][i][j] ----
// v2: occupancy 2x. 1024 blocks (256 bm x 4 ksp), 128 edges/block (2 m-tiles/wave), 1-kg chunks
// -> LDS 30.7KB dbuf, VGPR<=128 (launch_bounds 256,4) -> 4 blocks/CU, 16 waves/CU.
// Quarters write DISJOINT f16 ranges m[e][ksp*80+i] (single writer, no atomics).
__global__ __launch_bounds__(256, 4) void vgemm_kernel(
    const f16* __restrict__ ehh, const f16* __restrict__ hf,
    const f16* __restrict__ W2f, const int* __restrict__ Esrc,
    f16* __restrict__ m) {
  __shared__ __align__(16) f16 w2s[2][7680];     // 2 x 15360 B (1-kg chunks, fragment order)
  const int tid = threadIdx.x;
  const int bm = blockIdx.x & 255, ksp = blockIdx.x >> 8;
  const int e0 = bm * 128;
  const int kg0 = ksp * 20;
  const int wave = tid >> 6, lane = tid & 63;
  const int q = lane >> 4, mr = lane & 15;

  stage_bytes(W2f + kg0 * 7680, w2s[0], 15360, tid);

  // hf fragments in registers: wave owns 2 m-tiles (rows e0+wave*32+mt*16+mr)
  f16x8 hsv[2][3];
  size_t er80[2];
  #pragma unroll
  for (int mt = 0; mt < 2; ++mt) {
    int er = e0 + wave * 32 + mt * 16 + mr;
    int srcn = Esrc[er];
    er80[mt] = (size_t)er * 80;
    #pragma unroll
    for (int ks = 0; ks < 3; ++ks)
      hsv[mt][ks] = *(const f16x8*)(hf + (size_t)srcn * 96 + ks * 32 + q * 8);
  }

  f32x4 zero = {0.f, 0.f, 0.f, 0.f};
  f32x4 acc[2][5];
  #pragma unroll
  for (int mt = 0; mt < 2; ++mt)
    #pragma unroll
    for (int nt = 0; nt < 5; ++nt) acc[mt][nt] = zero;

  for (int ch = 0; ch < 20; ++ch) {
    // ev values for this chunk (1 kg): global->reg (L2-hot), issued before the barrier
    f16 ev0 = ehh[er80[0] + kg0 + ch];
    f16 ev1 = ehh[er80[1] + kg0 + ch];
    __syncthreads();                       // w2s[ch&1] staged
    if (ch + 1 < 20)
      stage_bytes(W2f + (kg0 + ch + 1) * 7680, w2s[(ch + 1) & 1], 15360, tid);
    const f16* wb = w2s[ch & 1];
    f16x8 af[2][3];
    f16x8 ev0v = {ev0, ev0, ev0, ev0, ev0, ev0, ev0, ev0};
    f16x8 ev1v = {ev1, ev1, ev1, ev1, ev1, ev1, ev1, ev1};
    #pragma unroll
    for (int ks = 0; ks < 3; ++ks) {
      af[0][ks] = hsv[0][ks] * ev0v;
      af[1][ks] = hsv[1][ks] * ev1v;
    }
    #pragma unroll
    for (int nt = 0; nt < 5; ++nt) {
      #pragma unroll
      for (int ks = 0; ks < 3; ++ks) {
        f16x8 bf = *(const f16x8*)(wb + (nt * 3 + ks) * 512 + lane * 8);  // base+lane*16: conflict-free
        acc[0][nt] = __builtin_amdgcn_mfma_f32_16x16x32_f16(af[0][ks], bf, acc[0][nt], 0, 0, 0);
        acc[1][nt] = __builtin_amdgcn_mfma_f32_16x16x32_f16(af[1][ks], bf, acc[1][nt], 0, 0, 0);
      }
    }
  }
  // epilogue: C layout col=lane&15, row=(lane>>4)*4+reg; f16 stores to disjoint quarter-row
  #pragma unroll
  for (int mt = 0; mt < 2; ++mt) {
    #pragma unroll
    for (int reg = 0; reg < 4; ++reg) {
      int er = e0 + wave * 32 + mt * 16 + q * 4 + reg;
      f16* mp = m + (size_t)er * 320 + ksp * 80;
      #pragma unroll
      for (int nt = 0; nt < 5; ++nt)
        mp[nt * 16 + mr] = (f16)acc[mt][nt][reg];
    }
  }
}

// ---------------- gather: agg[n,i] = sum over incoming edges of all 4 K-quarters (f16 in, fp32 acc) ----
// One output per thread (786K threads) -- scattered m-row reads need max TLP (r3 lesson).
__global__ void gather_kernel(const f16* __restrict__ m, const int* __restrict__ count,
                              const int* __restrict__ bucket, f16* __restrict__ aggf) {
  int t = blockIdx.x * 384 + threadIdx.x;  // exactly 8192*96
  int n = t / 96, i = t - n * 96;
  float s = 0.f;
  if (i < 80) {
    int cnt = count[n]; if (cnt > 64) cnt = 64;
    const int* bk = bucket + n * 64;
    for (int j = 0; j < cnt; ++j) {
      const f16* mp = m + (size_t)bk[j] * 320;
      s += ((float)mp[i] + (float)mp[80 + i]) + ((float)mp[160 + i] + (float)mp[240 + i]);
    }
  }
  aggf[t] = (f16)s;
}

// ---------------- fused GRU GEMMs + gate: 128 blocks x 64 rows; G never touches HBM ----------
// Waves 0,1 -> agg@WihT; waves 2,3 -> h@WhhT. A-tiles in LDS, B fragments direct from L2
// (wave-uniform rows, 22MB total -> L2-hot). Gate epilogue reads Gs from LDS.
__global__ __launch_bounds__(256, 1) void grufuse_kernel(
    const f16* __restrict__ aggf, const f16* __restrict__ hf,
    const f16* __restrict__ WihT, const f16* __restrict__ WhhT,
    const float* __restrict__ bih, const float* __restrict__ bhh,
    float* __restrict__ h, f16* __restrict__ hfout) {
  __shared__ __align__(16) f16 As[64 * 96];
  __shared__ __align__(16) f16 Hs[64 * 96];
  __shared__ __align__(16) f16 Gs[2][64][224];
  const int tid = threadIdx.x;
  const int n0 = blockIdx.x * 64;
  stage_bytes(aggf + (size_t)n0 * 96, As, 12288, tid);
  stage_bytes(hf + (size_t)n0 * 96, Hs, 12288, tid);
  const int w = tid >> 6, lane = tid & 63, q = lane >> 4, mr = lane & 15;
  const int g = w >> 1, sub = w & 1;
  const f16* Asrc = g ? Hs : As;
  const f16* B = g ? WhhT : WihT;
  __syncthreads();
  f16x8 af[2][3];
  #pragma unroll
  for (int mt = 0; mt < 2; ++mt)
    #pragma unroll
    for (int ks = 0; ks < 3; ++ks)
      af[mt][ks] = *(const f16x8*)(Asrc + (sub * 32 + mt * 16 + mr) * 96 + ks * 32 + q * 8);
  #pragma unroll
  for (int nt = 0; nt < 14; ++nt) {
    f32x4 acc[2];
    acc[0] = (f32x4){0.f, 0.f, 0.f, 0.f};
    acc[1] = (f32x4){0.f, 0.f, 0.f, 0.f};
    #pragma unroll
    for (int ks = 0; ks < 3; ++ks) {
      f16x8 bf = *(const f16x8*)(B + (nt * 16 + mr) * 96 + ks * 32 + q * 8);
      acc[0] = __builtin_amdgcn_mfma_f32_16x16x32_f16(af[0][ks], bf, acc[0], 0, 0, 0);
      acc[1] = __builtin_amdgcn_mfma_f32_16x16x32_f16(af[1][ks], bf, acc[1], 0, 0, 0);
    }
    #pragma unroll
    for (int mt = 0; mt < 2; ++mt)
      #pragma unroll
      for (int reg = 0; reg < 4; ++reg)
        Gs[g][sub * 32 + mt * 16 + q * 4 + reg][nt * 16 + mr] = (f16)acc[mt][reg];
  }
  __syncthreads();
  // gate: 64x73 elems
  for (int idx = tid; idx < 4672; idx += 256) {
    int n = idx / 73, i = idx - n * 73;
    float rr = (float)Gs[0][n][i] + bih[i] + (float)Gs[1][n][i] + bhh[i];
    rr = 1.f / (1.f + __expf(-rr));
    float zz = (float)Gs[0][n][73 + i] + bih[73 + i] + (float)Gs[1][n][73 + i] + bhh[73 + i];
    zz = 1.f / (1.f + __expf(-zz));
    float nx = (float)Gs[0][n][146 + i] + bih[146 + i] + rr * ((float)Gs[1][n][146 + i] + bhh[146 + i]);
    float nn_ = 2.f / (1.f + __expf(-2.f * nx)) - 1.f;
    size_t hi_ = (size_t)(n0 + n) * 96 + i;
    float hv = h[hi_];
    float hn = (1.f - zz) * nn_ + zz * hv;
    h[hi_] = hn;
    hfout[hi_] = (f16)hn;
  }
}

// ---------------- Set2Set helpers ----------------
__device__ __forceinline__ float wred_sum(float v) {
  #pragma unroll
  for (int off = 32; off; off >>= 1) v += __shfl_xor(v, off, 64);
  return v;
}
// fp32-accumulating f16 dots (v_dot2_f32_f16)
__device__ __forceinline__ float dot8(f16x8 w, f16x8 x, float acc) {
#if HAS_FDOT2
  acc = __builtin_amdgcn_fdot2((f16x2)__builtin_shufflevector(w, w, 0, 1),
                               (f16x2)__builtin_shufflevector(x, x, 0, 1), acc, false);
  acc = __builtin_amdgcn_fdot2((f16x2)__builtin_shufflevector(w, w, 2, 3),
                               (f16x2)__builtin_shufflevector(x, x, 2, 3), acc, false);
  acc = __builtin_amdgcn_fdot2((f16x2)__builtin_shufflevector(w, w, 4, 5),
                               (f16x2)__builtin_shufflevector(x, x, 4, 5), acc, false);
  acc = __builtin_amdgcn_fdot2((f16x2)__builtin_shufflevector(w, w, 6, 7),
                               (f16x2)__builtin_shufflevector(x, x, 6, 7), acc, false);
#else
  #pragma unroll
  for (int e = 0; e < 8; ++e) acc += (float)w[e] * (float)x[e];
#endif
  return acc;
}
__device__ __forceinline__ float dot4(f16x4 w, f16x4 x, float acc) {
#if HAS_FDOT2
  acc = __builtin_amdgcn_fdot2((f16x2)__builtin_shufflevector(w, w, 0, 1),
                               (f16x2)__builtin_shufflevector(x, x, 0, 1), acc, false);
  acc = __builtin_amdgcn_fdot2((f16x2)__builtin_shufflevector(w, w, 2, 3),
                               (f16x2)__builtin_shufflevector(x, x, 2, 3), acc, false);
#else
  #pragma unroll
  for (int e = 0; e < 4; ++e) acc += (float)w[e] * (float)x[e];
#endif
  return acc;
}

#define S2SCAP 256   // absolute per-segment cap (binomial mean 128, sd 11)
#define NCAP 190     // rows cached in LDS; [NCAP,segT) via global fallback (normally empty)

// ---------------- Set2Set v8: folded LSTM weights (q==hh -> K=152), unguarded P4 ----------
__global__ __launch_bounds__(512, 2) void s2s_kernel(
    const float* __restrict__ h, const f16* __restrict__ hf,
    const f16* __restrict__ Wcat,
    const float* __restrict__ lbih, const float* __restrict__ lbhh,
    const float* __restrict__ Wout, const float* __restrict__ bout,
    const int* __restrict__ segstarts, float* __restrict__ out) {
  __shared__ __align__(16) f16 hseg[NCAP * 84];   // 31920 B, row stride 84 f16 (b64-aligned)
  __shared__ __align__(16) f16 xcat[240];
  __shared__ float hhv[80];
  __shared__ float gatesv[292];
  __shared__ float earr[S2SCAP];
  __shared__ float red[4];
  __shared__ __align__(16) float rpart[19 * 80];
  const int t = threadIdx.x, b = blockIdx.x;
  const int wid = t >> 6, lane = t & 63;

  const int s0 = segstarts[b];
  int segT = segstarts[b + 1] - s0;
  if (segT > S2SCAP) segT = S2SCAP;
  const int c = segT < NCAP ? segT : NCAP;

  if (t < 240) xcat[t] = (f16)0.f;
  if (t < 80) hhv[t] = 0.f;
  if (t < S2SCAP) earr[t] = 0.f;   // pre-zero so P4 runs unguarded

  // stage hseg rows (f16, cols 0..75 data incl. zero pads 73..75; cols 76..83 zeroed);
  // rows [c, NCAP) fully zeroed so P4 needs no per-row guard (0*0 contributions)
  for (int r = wid; r < NCAP; r += 8) {
    if (lane < 21) {
      f16x4 v = {(f16)0.f, (f16)0.f, (f16)0.f, (f16)0.f};
      if (r < c && lane < 19)
        v = *(const f16x4*)(hf + (size_t)(s0 + r) * 96 + lane * 4);
      *(f16x4*)(hseg + r * 84 + lane * 4) = v;
    }
  }

  const bool isg = (t >= 220);
  const int g2 = t - 220;
  float bias = 0.f;
  if (isg) bias = lbih[g2] + lbhh[g2];
  // Folded LSTM weight row RESIDENT in registers (q==hh: Wcat[0..72]=wih_q+whh, [76..148]=wih_r)
  f16x8 wihF[19];
  {
    const f16* wr = Wcat + (size_t)(isg ? g2 : 0) * 232;
    #pragma unroll
    for (int v = 0; v < 19; ++v) wihF[v] = *(const f16x8*)(wr + v * 8);
  }
  const int nc = t / 10, fo = t - nc * 10;    // readout mapping (t<190)
  float creg = 0.f;                            // LSTM cell state (t<73)
  __syncthreads();

  for (int iter = 0; iter < 12; ++iter) {
    // ---- P1: LSTM gate matvec (292 threads), folded K=152, 4 accumulators ----
    if (isg) {
      float a0 = bias, a1 = 0.f, a2 = 0.f, a3 = 0.f;
      #pragma unroll
      for (int v = 0; v < 19; ++v) {
        f16x8 x = *(const f16x8*)(xcat + v * 8);
        int sel = v & 3;
        if (sel == 0) a0 = dot8(wihF[v], x, a0);
        else if (sel == 1) a1 = dot8(wihF[v], x, a1);
        else if (sel == 2) a2 = dot8(wihF[v], x, a2);
        else a3 = dot8(wihF[v], x, a3);
      }
      gatesv[g2] = (a0 + a1) + (a2 + a3);
    }
    __syncthreads();
    // ---- P2: LSTM elementwise update (t<73) ----
    if (t < 73) {
      float ig = 1.f / (1.f + __expf(-gatesv[t]));
      float fg = 1.f / (1.f + __expf(-gatesv[73 + t]));
      float gx = gatesv[146 + t];
      float gg = 2.f / (1.f + __expf(-2.f * gx)) - 1.f;
      float og = 1.f / (1.f + __expf(-gatesv[219 + t]));
      creg = fg * creg + ig * gg;
      float cth = 2.f / (1.f + __expf(-2.f * creg)) - 1.f;
      float hh = og * cth;
      hhv[t] = hh;
      xcat[t] = (f16)hh;        // q slot (doubles as hh via folded weights)
    }
    __syncthreads();
    // ---- P3: logits + exp + per-wave sums (t<192, node per thread, f16 dot) ----
    if (wid < 3) {
      float a = 0.f;
      if (t < c) {
        const f16* hp = hseg + t * 84;
        float e0 = 0.f, e1 = 0.f;
        #pragma unroll
        for (int k = 0; k < 9; ++k) {
          f16x4 h0 = *(const f16x4*)(hp + 8 * k);
          f16x4 h1 = *(const f16x4*)(hp + 8 * k + 4);
          f16x4 x0 = *(const f16x4*)(xcat + 8 * k);
          f16x4 x1 = *(const f16x4*)(xcat + 8 * k + 4);
          e0 = dot4(h0, x0, e0);
          e1 = dot4(h1, x1, e1);
        }
        f16x4 ht = *(const f16x4*)(hp + 72);
        f16x4 xt = *(const f16x4*)(xcat + 72);
        e0 = dot4(ht, xt, e0);
        a = __expf(fminf(e0 + e1, 80.f));  // logits bounded; no max-sub in fp32
        earr[t] = a;
      }
      float ws = wred_sum(a);
      if (lane == 0) red[wid] = ws;
    }
    // fallback logits for nodes >= NCAP (normally zero-trip)
    if (wid == 0) {
      float fa = 0.f;
      int n = NCAP + lane;
      if (n < segT) {
        const float* hr = h + (size_t)(s0 + n) * 96;
        float e = 0.f;
        for (int i = 0; i < 73; ++i) e += hr[i] * hhv[i];
        fa = __expf(fminf(e, 80.f));
        earr[n] = fa;
      }
      float ws2 = wred_sum(fa);
      if (lane == 0) red[3] = ws2;
    }
    __syncthreads();
    // ---- P4: weighted readout partials (unguarded: earr/hseg zero-padded) ----
    if (t < 190) {
      float r0 = 0.f, r1 = 0.f, r2 = 0.f, r3 = 0.f, r4 = 0.f, r5 = 0.f, r6 = 0.f, r7 = 0.f;
      #pragma unroll
      for (int j = 0; j < 10; ++j) {
        int n = nc * 10 + j;
        float a = earr[n];
        const f16* hp = hseg + n * 84 + fo * 8;
        f16x4 v0 = *(const f16x4*)(hp);
        f16x4 v1 = *(const f16x4*)(hp + 4);
        r0 += a * (float)v0[0]; r1 += a * (float)v0[1];
        r2 += a * (float)v0[2]; r3 += a * (float)v0[3];
        r4 += a * (float)v1[0]; r5 += a * (float)v1[1];
        r6 += a * (float)v1[2]; r7 += a * (float)v1[3];
      }
      if (nc == 18) {  // fallback nodes from global hf (normally zero-trip)
        for (int n = NCAP; n < segT; ++n) {
          float a = earr[n];
          const f16* hp = hf + (size_t)(s0 + n) * 96 + fo * 8;
          f16x4 v0 = *(const f16x4*)(hp);
          f16x4 v1 = *(const f16x4*)(hp + 4);
          r0 += a * (float)v0[0]; r1 += a * (float)v0[1];
          r2 += a * (float)v0[2]; r3 += a * (float)v0[3];
          r4 += a * (float)v1[0]; r5 += a * (float)v1[1];
          r6 += a * (float)v1[2]; r7 += a * (float)v1[3];
        }
      }
      f32x4 wa = {r0, r1, r2, r3}, wb = {r4, r5, r6, r7};
      *(f32x4*)(rpart + nc * 80 + fo * 8) = wa;
      *(f32x4*)(rpart + nc * 80 + fo * 8 + 4) = wb;
    }
    __syncthreads();
    // ---- P5: combine partials -> r into xcat (t<80) ----
    if (t < 80) {
      float S = red[0] + red[1] + red[2] + red[3];
      float invS = (S > 0.f) ? (1.f / S) : 0.f;
      float r = 0.f;
      #pragma unroll
      for (int ch = 0; ch < 19; ++ch) r += rpart[ch * 80 + t];
      if (t < 73) xcat[76 + t] = (f16)(r * invS);
    }
    __syncthreads();
  }
  // ---- output: out[b] = bout + hh . Wout ----
  if (t < 80) gatesv[t] = (t < 73) ? hhv[t] * Wout[t] : 0.f;
  __syncthreads();
  if (t == 0) {
    float a = bout[0];
    for (int i = 0; i < 73; ++i) a += gatesv[i];
    out[b] = a;
  }
}

// ---------------- workspace layout (bytes; ws_size = 256 MiB per harness fill) ----------------
#define OFF_H      0u          // float [8192][96]
#define OFF_HF     17825792u   // f16 [8192][96]
#define OFF_AGGF   19398656u   // f16 [8192][96]
#define OFF_EHH    20971520u   // f16 [32768][80]
#define OFF_W2F    26214400u   // f16 [80][7680] fragment order
#define OFF_WIHT   27443200u   // f16 [224][96]
#define OFF_WHHT   27486208u   // f16 [224][96]
#define OFF_WCAT   27529216u   // f16 [292][232]
#define OFF_SEG    27664704u   // int [65]
#define OFF_CNT    27665024u   // int [8192]
#define OFF_BKT    27697792u   // int [8192][64]
#define OFF_M      29794944u   // f16 [32768][320] K-quarter partials (end ~50.8 MB)

extern "C" void kernel_launch(void* const* d_in, const int* in_sizes, int n_in,
                              void* d_out, int out_size, void* d_ws, size_t ws_size,
                              hipStream_t stream) {
  const float* nf   = (const float*)d_in[0];
  const float* ef   = (const float*)d_in[1];
  const float* W_in = (const float*)d_in[2];
  const float* b_in = (const float*)d_in[3];
  const float* W1   = (const float*)d_in[4];
  const float* b1   = (const float*)d_in[5];
  const float* W2   = (const float*)d_in[6];
  const float* b2   = (const float*)d_in[7];
  const float* gWih = (const float*)d_in[8];
  const float* gWhh = (const float*)d_in[9];
  const float* gbih = (const float*)d_in[10];
  const float* gbhh = (const float*)d_in[11];
  const float* lWih = (const float*)d_in[12];
  const float* lWhh = (const float*)d_in[13];
  const float* lbih = (const float*)d_in[14];
  const float* lbhh = (const float*)d_in[15];
  const float* Wout = (const float*)d_in[16];
  const float* bout = (const float*)d_in[17];
  const int* Esrc   = (const int*)d_in[18];
  const int* Etgt   = (const int*)d_in[19];
  const int* batch  = (const int*)d_in[20];

  char* ws = (char*)d_ws;
  float* h    = (float*)(ws + OFF_H);
  f16* hf     = (f16*)(ws + OFF_HF);
  f16* aggf   = (f16*)(ws + OFF_AGGF);
  f16* ehh    = (f16*)(ws + OFF_EHH);
  f16* W2f    = (f16*)(ws + OFF_W2F);
  f16* WihT   = (f16*)(ws + OFF_WIHT);
  f16* WhhT   = (f16*)(ws + OFF_WHHT);
  f16* Wcat   = (f16*)(ws + OFF_WCAT);
  int* segst  = (int*)(ws + OFF_SEG);
  int* cnt    = (int*)(ws + OFF_CNT);
  int* bkt    = (int*)(ws + OFF_BKT);
  f16* m      = (f16*)(ws + OFF_M);

  hipMemsetAsync(cnt, 0, NN * sizeof(int), stream);
  prep_kernel<<<16273, 256, 0, stream>>>(nf, ef, W_in, b_in, W1, b1, W2, b2,
                                         gWih, gWhh, lWih, lWhh, batch, Etgt,
                                         h, hf, ehh, W2f, WihT, WhhT, Wcat,
                                         segst, cnt, bkt);
  for (int step = 0; step < 3; ++step) {
    vgemm_kernel<<<1024, 256, 0, stream>>>(ehh, hf, W2f, Esrc, m);
    gather_kernel<<<2048, 384, 0, stream>>>(m, cnt, bkt, aggf);
    grufuse_kernel<<<128, 256, 0, stream>>>(aggf, hf, WihT, WhhT, gbih, gbhh, h, hf);
  }
  s2s_kernel<<<64, 512, 0, stream>>>(h, hf, Wcat, lbih, lbhh, Wout, bout, segst,
                                     (float*)d_out);
}

// Round 5
// 323.732 us; speedup vs baseline: 1.4613x; 1.0669x over previous
//
#include <hip/hip_runtime.h>

typedef _Float16 f16;
typedef f16 f16x2 __attribute__((ext_vector_type(2)));
typedef f16 f16x4 __attribute__((ext_vector_type(4)));
typedef f16 f16x8 __attribute__((ext_vector_type(8)));
typedef float f32x4 __attribute__((ext_vector_type(4)));

#define AS1 __attribute__((address_space(1)))
#define AS3 __attribute__((address_space(3)))

#define NN 8192
#define EE 32768

#if __has_builtin(__builtin_amdgcn_fdot2)
#define HAS_FDOT2 1
#else
#define HAS_FDOT2 0
#endif

__device__ __forceinline__ void glds16(const void* g, void* l) {
  __builtin_amdgcn_global_load_lds((const AS1 unsigned int*)g, (AS3 unsigned int*)l, 16, 0, 0);
}
// cooperative stage, 256 threads, 16B/lane; LDS base passed wave-uniform
__device__ __forceinline__ void stage_bytes(const void* g, void* s, int nbytes, int tid) {
  const int lane = tid & 63;
  for (int off = tid * 16; off < nbytes; off += 4096)
    glds16((const char*)g + off, (char*)s + (off - lane * 16));
}

// ---------------- prep: h0 GEMM, ehh, W2 fragment repack (pad 16KB/kg), weight casts, segstarts, CSR ----
__global__ void prep_kernel(
    const float* __restrict__ nf, const float* __restrict__ ef,
    const float* __restrict__ W_in, const float* __restrict__ b_in,
    const float* __restrict__ W1, const float* __restrict__ b1,
    const float* __restrict__ W2, const float* __restrict__ b2,
    const float* __restrict__ gWih, const float* __restrict__ gWhh,
    const float* __restrict__ lWih, const float* __restrict__ lWhh,
    const int* __restrict__ batch, const int* __restrict__ Etgt,
    float* __restrict__ h, f16* __restrict__ hf, f16* __restrict__ ehh,
    f16* __restrict__ W2f, f16* __restrict__ WihT, f16* __restrict__ WhhT,
    f16* __restrict__ Wcat, int* __restrict__ segstarts,
    int* __restrict__ count, int* __restrict__ bucket) {
  int t = blockIdx.x * 256 + threadIdx.x;
  if (t < 786432) {                       // h0: [8192][96] fp32+f16, pads zero
    int n = t / 96, i = t - n * 96;
    float v = 0.f;
    if (i < 73) {
      v = b_in[i];
      const float* nr = nf + n * 32;
      #pragma unroll
      for (int f = 0; f < 32; ++f) v += nr[f] * W_in[f * 73 + i];
    }
    h[t] = v; hf[t] = (f16)v;
    return;
  }
  t -= 786432;
  if (t < 2621440) {                      // ehh: [32768][80], col73 = 1.0 (bias), cols 74-79 zero
    int e = t / 80, k = t - e * 80;
    float v;
    if (k < 73) {
      v = b1[k];
      const float* er = ef + e * 16;
      #pragma unroll
      for (int f = 0; f < 16; ++f) v += er[f] * W1[f * 73 + k];
      v = fmaxf(v, 0.f);
    } else v = (k == 73) ? 1.f : 0.f;
    ehh[t] = (f16)v;
    return;
  }
  t -= 2621440;
  if (t < 655360) {                       // W2f: [80 kg][8192]: data [5 nt][3 ks][64 lane][8] + 512 pad
    int kg = t / 8192, r = t - kg * 8192;
    float v = 0.f;
    if (r < 7680) {
      int nt = r / 1536, r2 = r - nt * 1536;
      int ks = r2 / 512, r3 = r2 - ks * 512;
      int l = r3 >> 3, j = r3 & 7;
      int mr = l & 15, q = l >> 4;
      int i = nt * 16 + mr, jj = ks * 32 + q * 8 + j;
      if (i < 73 && jj < 73) {
        if (kg < 73) v = W2[kg * 5329 + i * 73 + jj];
        else if (kg == 73) v = b2[i * 73 + jj];
      }
    }
    W2f[t] = (f16)v;
    return;
  }
  t -= 655360;
  if (t < 43008) {                        // WihT/WhhT: [224][96]
    int half = t / 21504, r = t - half * 21504;
    int g = r / 96, k = r - g * 96;
    float v = 0.f;
    if (g < 219 && k < 73) v = half ? gWhh[g * 73 + k] : gWih[g * 73 + k];
    (half ? WhhT : WihT)[r] = (f16)v;
    return;
  }
  t -= 43008;
  if (t < 67744) {                        // Wcat[292][232]: q==hh fold -> [0..72]=wih_q+whh [76..148]=wih_r
    int g = t / 232, k = t - g * 232;
    float v = 0.f;
    if (k < 73) v = lWih[g * 146 + k] + lWhh[g * 73 + k];
    else if (k >= 76 && k < 149) v = lWih[g * 146 + (k - 3)];
    Wcat[t] = (f16)v;
    return;
  }
  t -= 67744;
  if (t < 65) {                           // segstarts: lower_bound(batch, t)
    int key = t, lo = 0, hi = NN;
    while (lo < hi) { int mid = (lo + hi) >> 1; if (batch[mid] < key) lo = mid + 1; else hi = mid; }
    segstarts[t] = lo;
    return;
  }
  t -= 65;
  if (t < EE) {                           // bucket fill: CSR-by-target (cap 64, lambda=4)
    int tg = Etgt[t];
    int slot = atomicAdd(&count[tg], 1);
    if (slot < 64) bucket[tg * 64 + slot] = t;
  }
}

// ---------------- edge-network matvec: m[e,i] = sum_{kg,j} ehh[e,kg] * hf[src[e],j] * W2[kg][i][j] ----
// v3: counted-vmcnt 3-buffer ring (T3/T4). 512 blocks (128 bm x 4 ksp), 256 edges/block,
// 4 m-tiles/wave (each ds_read_b128 feeds 4 MFMA -> MFMA-bound). Per iter EXACTLY 4 vmem ops
// (stage 16KB = 4 glds16/thread); ehh slice pre-staged to LDS so the vmcnt count is exact.
// stage(ch+1) -> s_waitcnt vmcnt(4) -> raw s_barrier: prefetch stays in flight across barriers.
__global__ __launch_bounds__(256, 2) void vgemm_kernel(
    const f16* __restrict__ ehh, const f16* __restrict__ hf,
    const f16* __restrict__ W2f, const int* __restrict__ Esrc,
    f16* __restrict__ m) {
  __shared__ __align__(16) f16 w2s[3][8192];     // 3 x 16 KB ring (write buf != both live read bufs)
  __shared__ __align__(16) f16 ehsl[256 * 20];   // ehh slice [row][20]
  const int tid = threadIdx.x;
  const int bm = blockIdx.x & 127, ksp = blockIdx.x >> 7;
  const int e0 = bm * 256;
  const int kg0 = ksp * 20;
  const int wave = tid >> 6, lane = tid & 63;
  const int q = lane >> 4, mr = lane & 15;

  // ehh slice -> LDS (row tid, 20 cols); 8B-aligned f16x4 ops
  {
    const f16* er = ehh + (size_t)(e0 + tid) * 80 + kg0;
    #pragma unroll
    for (int p = 0; p < 5; ++p)
      *(f16x4*)(ehsl + tid * 20 + p * 4) = *(const f16x4*)(er + p * 4);
  }
  // hf fragments in registers: wave owns 4 m-tiles (rows e0+wave*64+mt*16+mr)
  f16x8 hsv[4][3];
  #pragma unroll
  for (int mt = 0; mt < 4; ++mt) {
    int er = e0 + wave * 64 + mt * 16 + mr;
    int srcn = Esrc[er];
    #pragma unroll
    for (int ks = 0; ks < 3; ++ks)
      hsv[mt][ks] = *(const f16x8*)(hf + (size_t)srcn * 96 + ks * 32 + q * 8);
  }
  f32x4 zero = {0.f, 0.f, 0.f, 0.f};
  f32x4 acc[4][5];
  #pragma unroll
  for (int mt = 0; mt < 4; ++mt)
    #pragma unroll
    for (int nt = 0; nt < 5; ++nt) acc[mt][nt] = zero;

  __syncthreads();                 // ehsl visible; full drain -> clean vmcnt slate
  stage_bytes(W2f + (size_t)kg0 * 8192, w2s[0], 16384, tid);   // chunk 0: 4 loads/thread

  int rd = 0;
  for (int ch = 0; ch < 20; ++ch) {
    if (ch < 19) {
      int wr = rd + 1; if (wr == 3) wr = 0;
      stage_bytes(W2f + (size_t)(kg0 + ch + 1) * 8192, w2s[wr], 16384, tid);
      asm volatile("s_waitcnt vmcnt(4)" ::: "memory");   // chunk ch's 4 older loads done
    } else {
      asm volatile("s_waitcnt vmcnt(0)" ::: "memory");   // last chunk: full drain
    }
    __builtin_amdgcn_s_barrier();
    const f16* wb = w2s[rd];
    f16 ev[4];
    #pragma unroll
    for (int mt = 0; mt < 4; ++mt)
      ev[mt] = ehsl[(wave * 64 + mt * 16 + mr) * 20 + ch];
    f16x8 af[4][3];
    #pragma unroll
    for (int mt = 0; mt < 4; ++mt) {
      f16 e = ev[mt];
      f16x8 evv = {e, e, e, e, e, e, e, e};
      #pragma unroll
      for (int ks = 0; ks < 3; ++ks) af[mt][ks] = hsv[mt][ks] * evv;
    }
    __builtin_amdgcn_s_setprio(1);
    #pragma unroll
    for (int nt = 0; nt < 5; ++nt) {
      #pragma unroll
      for (int ks = 0; ks < 3; ++ks) {
        f16x8 bf = *(const f16x8*)(wb + (nt * 3 + ks) * 512 + lane * 8);  // conflict-free
        #pragma unroll
        for (int mt = 0; mt < 4; ++mt)
          acc[mt][nt] = __builtin_amdgcn_mfma_f32_16x16x32_f16(af[mt][ks], bf, acc[mt][nt], 0, 0, 0);
      }
    }
    __builtin_amdgcn_s_setprio(0);
    rd = rd + 1; if (rd == 3) rd = 0;
  }
  // epilogue: C layout col=lane&15, row=(lane>>4)*4+reg; f16 stores to disjoint quarter-row
  #pragma unroll
  for (int mt = 0; mt < 4; ++mt) {
    #pragma unroll
    for (int reg = 0; reg < 4; ++reg) {
      int er = e0 + wave * 64 + mt * 16 + q * 4 + reg;
      f16* mp = m + (size_t)er * 320 + ksp * 80;
      #pragma unroll
      for (int nt = 0; nt < 5; ++nt)
        mp[nt * 16 + mr] = (f16)acc[mt][nt][reg];
    }
  }
}

// ---------------- gather: agg[n,i] = sum over incoming edges of all 4 K-quarters (f16 in, fp32 acc) ----
// One output per thread (786K threads) -- scattered m-row reads need max TLP.
__global__ void gather_kernel(const f16* __restrict__ m, const int* __restrict__ count,
                              const int* __restrict__ bucket, f16* __restrict__ aggf) {
  int t = blockIdx.x * 384 + threadIdx.x;  // exactly 8192*96
  int n = t / 96, i = t - n * 96;
  float s = 0.f;
  if (i < 80) {
    int cnt = count[n]; if (cnt > 64) cnt = 64;
    const int* bk = bucket + n * 64;
    for (int j = 0; j < cnt; ++j) {
      const f16* mp = m + (size_t)bk[j] * 320;
      s += ((float)mp[i] + (float)mp[80 + i]) + ((float)mp[160 + i] + (float)mp[240 + i]);
    }
  }
  aggf[t] = (f16)s;
}

// ---------------- GRU gates GEMMs: G[0]=agg@WihT, G[1]=h@WhhT (G stored f16) ----------------
__global__ __launch_bounds__(256, 1) void grugemm_kernel(
    const f16* __restrict__ aggf, const f16* __restrict__ hf,
    const f16* __restrict__ WihT, const f16* __restrict__ WhhT,
    f16* __restrict__ G) {
  __shared__ __align__(16) f16 As[128 * 96];
  __shared__ __align__(16) f16 Bs[224 * 96];
  const int tid = threadIdx.x;
  const int bz = blockIdx.x >> 6, bm = blockIdx.x & 63;
  const int m0 = bm * 128;
  const f16* A = bz ? hf : aggf;
  const f16* B = bz ? WhhT : WihT;
  f16* out = G + bz * (NN * 224);
  stage_bytes(A + m0 * 96, As, 128 * 96 * 2, tid);
  stage_bytes(B, Bs, 224 * 96 * 2, tid);
  const int wave = tid >> 6, lane = tid & 63, q = lane >> 4, mr = lane & 15;
  __syncthreads();
  f16x8 af[2][3];
  #pragma unroll
  for (int mt = 0; mt < 2; ++mt)
    #pragma unroll
    for (int ks = 0; ks < 3; ++ks)
      af[mt][ks] = *(const f16x8*)(As + (wave * 32 + mt * 16 + mr) * 96 + ks * 32 + q * 8);
  f32x4 zero = {0.f, 0.f, 0.f, 0.f};
  f32x4 acc[2][14];
  #pragma unroll
  for (int mt = 0; mt < 2; ++mt)
    #pragma unroll
    for (int nt = 0; nt < 14; ++nt) acc[mt][nt] = zero;
  #pragma unroll
  for (int nt = 0; nt < 14; ++nt) {
    #pragma unroll
    for (int ks = 0; ks < 3; ++ks) {
      f16x8 bf = *(const f16x8*)(Bs + (nt * 16 + mr) * 96 + ks * 32 + q * 8);
      #pragma unroll
      for (int mt = 0; mt < 2; ++mt)
        acc[mt][nt] = __builtin_amdgcn_mfma_f32_16x16x32_f16(af[mt][ks], bf, acc[mt][nt], 0, 0, 0);
    }
  }
  #pragma unroll
  for (int mt = 0; mt < 2; ++mt)
    #pragma unroll
    for (int reg = 0; reg < 4; ++reg) {
      int row = m0 + wave * 32 + mt * 16 + q * 4 + reg;
      #pragma unroll
      for (int nt = 0; nt < 14; ++nt)
        out[row * 224 + nt * 16 + mr] = (f16)acc[mt][nt][reg];
    }
}

// ---------------- GRU elementwise update (G in f16) ----------------
__global__ void gate_kernel(const f16* __restrict__ G, const float* __restrict__ bih,
                            const float* __restrict__ bhh, float* __restrict__ h,
                            f16* __restrict__ hf) {
  int idx = blockIdx.x * 256 + threadIdx.x;  // exactly 8192*73
  int n = idx / 73, i = idx - n * 73;
  const f16* g0 = G + n * 224;
  const f16* g1 = G + NN * 224 + n * 224;
  float rr = (float)g0[i] + bih[i] + (float)g1[i] + bhh[i];
  rr = 1.f / (1.f + __expf(-rr));
  float zz = (float)g0[73 + i] + bih[73 + i] + (float)g1[73 + i] + bhh[73 + i];
  zz = 1.f / (1.f + __expf(-zz));
  float nx = (float)g0[146 + i] + bih[146 + i] + rr * ((float)g1[146 + i] + bhh[146 + i]);
  float nn_ = 2.f / (1.f + __expf(-2.f * nx)) - 1.f;
  float hv = h[n * 96 + i];
  float hn = (1.f - zz) * nn_ + zz * hv;
  h[n * 96 + i] = hn;
  hf[n * 96 + i] = (f16)hn;
}

// ---------------- Set2Set helpers ----------------
__device__ __forceinline__ float wred_sum(float v) {
  #pragma unroll
  for (int off = 32; off; off >>= 1) v += __shfl_xor(v, off, 64);
  return v;
}
// fp32-accumulating f16 dots (v_dot2_f32_f16)
__device__ __forceinline__ float dot8(f16x8 w, f16x8 x, float acc) {
#if HAS_FDOT2
  acc = __builtin_amdgcn_fdot2((f16x2)__builtin_shufflevector(w, w, 0, 1),
                               (f16x2)__builtin_shufflevector(x, x, 0, 1), acc, false);
  acc = __builtin_amdgcn_fdot2((f16x2)__builtin_shufflevector(w, w, 2, 3),
                               (f16x2)__builtin_shufflevector(x, x, 2, 3), acc, false);
  acc = __builtin_amdgcn_fdot2((f16x2)__builtin_shufflevector(w, w, 4, 5),
                               (f16x2)__builtin_shufflevector(x, x, 4, 5), acc, false);
  acc = __builtin_amdgcn_fdot2((f16x2)__builtin_shufflevector(w, w, 6, 7),
                               (f16x2)__builtin_shufflevector(x, x, 6, 7), acc, false);
#else
  #pragma unroll
  for (int e = 0; e < 8; ++e) acc += (float)w[e] * (float)x[e];
#endif
  return acc;
}
__device__ __forceinline__ float dot4(f16x4 w, f16x4 x, float acc) {
#if HAS_FDOT2
  acc = __builtin_amdgcn_fdot2((f16x2)__builtin_shufflevector(w, w, 0, 1),
                               (f16x2)__builtin_shufflevector(x, x, 0, 1), acc, false);
  acc = __builtin_amdgcn_fdot2((f16x2)__builtin_shufflevector(w, w, 2, 3),
                               (f16x2)__builtin_shufflevector(x, x, 2, 3), acc, false);
#else
  #pragma unroll
  for (int e = 0; e < 4; ++e) acc += (float)w[e] * (float)x[e];
#endif
  return acc;
}

#define S2SCAP 256   // absolute per-segment cap (binomial mean 128, sd 11)
#define NCAP 190     // rows cached in LDS; [NCAP,segT) via global fallback (normally empty)

// ---------------- Set2Set v9: + register-pinned hseg rows (P3) and blocks (P4) ----------
// P3/P4 hseg addresses are loop-invariant per thread -> pin in VGPRs, removing ~40 dependent
// LDS loads (~120cyc each) from each of the 12 serial iterations.
__global__ __launch_bounds__(512, 2) void s2s_kernel(
    const float* __restrict__ h, const f16* __restrict__ hf,
    const f16* __restrict__ Wcat,
    const float* __restrict__ lbih, const float* __restrict__ lbhh,
    const float* __restrict__ Wout, const float* __restrict__ bout,
    const int* __restrict__ segstarts, float* __restrict__ out) {
  __shared__ __align__(16) f16 hseg[NCAP * 84];   // 31920 B, row stride 84 f16 (b64-aligned)
  __shared__ __align__(16) f16 xcat[240];
  __shared__ float hhv[80];
  __shared__ float gatesv[292];
  __shared__ float earr[S2SCAP];
  __shared__ float red[4];
  __shared__ __align__(16) float rpart[19 * 80];
  const int t = threadIdx.x, b = blockIdx.x;
  const int wid = t >> 6, lane = t & 63;

  const int s0 = segstarts[b];
  int segT = segstarts[b + 1] - s0;
  if (segT > S2SCAP) segT = S2SCAP;
  const int c = segT < NCAP ? segT : NCAP;

  if (t < 240) xcat[t] = (f16)0.f;
  if (t < 80) hhv[t] = 0.f;
  if (t < S2SCAP) earr[t] = 0.f;   // pre-zero so P4 runs unguarded

  // stage hseg rows (f16, cols 0..75 data incl. zero pads 73..75; cols 76..83 zeroed);
  // rows [c, NCAP) fully zeroed so P4 needs no per-row guard (0*0 contributions)
  for (int r = wid; r < NCAP; r += 8) {
    if (lane < 21) {
      f16x4 v = {(f16)0.f, (f16)0.f, (f16)0.f, (f16)0.f};
      if (r < c && lane < 19)
        v = *(const f16x4*)(hf + (size_t)(s0 + r) * 96 + lane * 4);
      *(f16x4*)(hseg + r * 84 + lane * 4) = v;
    }
  }

  const bool isg = (t >= 220);
  const int g2 = t - 220;
  float bias = 0.f;
  if (isg) bias = lbih[g2] + lbhh[g2];
  // Folded LSTM weight row RESIDENT in registers (q==hh: Wcat[0..72]=wih_q+whh, [76..148]=wih_r)
  f16x8 wihF[19];
  {
    const f16* wr = Wcat + (size_t)(isg ? g2 : 0) * 232;
    #pragma unroll
    for (int v = 0; v < 19; ++v) wihF[v] = *(const f16x8*)(wr + v * 8);
  }
  const int nc = t / 10, fo = t - nc * 10;    // readout mapping (t<190)
  float creg = 0.f;                            // LSTM cell state (t<73)
  __syncthreads();                             // hseg staged & visible

  // ---- register pinning (loop-invariant LDS reads, clamped for inactive threads) ----
  f16x4 hrow[19];                              // P3: own hseg row (t<190; rows>=c are zero)
  {
    const f16* hp = hseg + (t < NCAP ? t : 0) * 84;
    #pragma unroll
    for (int k = 0; k < 19; ++k) hrow[k] = *(const f16x4*)(hp + k * 4);
  }
  f16x4 hb0[10], hb1[10];                      // P4: 10-node block at feature-octet fo
  {
    int ncc = (t < 190) ? nc : 0, foc = (t < 190) ? fo : 0;
    #pragma unroll
    for (int j = 0; j < 10; ++j) {
      const f16* hp = hseg + (ncc * 10 + j) * 84 + foc * 8;
      hb0[j] = *(const f16x4*)(hp);
      hb1[j] = *(const f16x4*)(hp + 4);
    }
  }

  for (int iter = 0; iter < 12; ++iter) {
    // ---- P1: LSTM gate matvec (292 threads), folded K=152, 4 accumulators ----
    if (isg) {
      float a0 = bias, a1 = 0.f, a2 = 0.f, a3 = 0.f;
      #pragma unroll
      for (int v = 0; v < 19; ++v) {
        f16x8 x = *(const f16x8*)(xcat + v * 8);
        int sel = v & 3;
        if (sel == 0) a0 = dot8(wihF[v], x, a0);
        else if (sel == 1) a1 = dot8(wihF[v], x, a1);
        else if (sel == 2) a2 = dot8(wihF[v], x, a2);
        else a3 = dot8(wihF[v], x, a3);
      }
      gatesv[g2] = (a0 + a1) + (a2 + a3);
    }
    __syncthreads();
    // ---- P2: LSTM elementwise update (t<73) ----
    if (t < 73) {
      float ig = 1.f / (1.f + __expf(-gatesv[t]));
      float fg = 1.f / (1.f + __expf(-gatesv[73 + t]));
      float gx = gatesv[146 + t];
      float gg = 2.f / (1.f + __expf(-2.f * gx)) - 1.f;
      float og = 1.f / (1.f + __expf(-gatesv[219 + t]));
      creg = fg * creg + ig * gg;
      float cth = 2.f / (1.f + __expf(-2.f * creg)) - 1.f;
      float hh = og * cth;
      hhv[t] = hh;
      xcat[t] = (f16)hh;        // q slot (doubles as hh via folded weights)
    }
    __syncthreads();
    // ---- P3: logits + exp + per-wave sums (t<192; hseg row from REGISTERS) ----
    if (wid < 3) {
      float a = 0.f;
      if (t < c) {
        float e0 = 0.f, e1 = 0.f;
        #pragma unroll
        for (int k = 0; k < 19; ++k) {
          f16x4 xk = *(const f16x4*)(xcat + k * 4);
          if (k & 1) e1 = dot4(hrow[k], xk, e1);
          else e0 = dot4(hrow[k], xk, e0);
        }
        a = __expf(fminf(e0 + e1, 80.f));  // logits bounded; no max-sub in fp32
        earr[t] = a;
      }
      float ws = wred_sum(a);
      if (lane == 0) red[wid] = ws;
    }
    // fallback logits for nodes >= NCAP (normally zero-trip)
    if (wid == 0) {
      float fa = 0.f;
      int n = NCAP + lane;
      if (n < segT) {
        const float* hr = h + (size_t)(s0 + n) * 96;
        float e = 0.f;
        for (int i = 0; i < 73; ++i) e += hr[i] * hhv[i];
        fa = __expf(fminf(e, 80.f));
        earr[n] = fa;
      }
      float ws2 = wred_sum(fa);
      if (lane == 0) red[3] = ws2;
    }
    __syncthreads();
    // ---- P4: weighted readout partials (hseg block from REGISTERS; earr zero-padded) ----
    if (t < 190) {
      float r0 = 0.f, r1 = 0.f, r2 = 0.f, r3 = 0.f, r4 = 0.f, r5 = 0.f, r6 = 0.f, r7 = 0.f;
      #pragma unroll
      for (int j = 0; j < 10; ++j) {
        float a = earr[nc * 10 + j];
        r0 += a * (float)hb0[j][0]; r1 += a * (float)hb0[j][1];
        r2 += a * (float)hb0[j][2]; r3 += a * (float)hb0[j][3];
        r4 += a * (float)hb1[j][0]; r5 += a * (float)hb1[j][1];
        r6 += a * (float)hb1[j][2]; r7 += a * (float)hb1[j][3];
      }
      if (nc == 18) {  // fallback nodes from global hf (normally zero-trip)
        for (int n = NCAP; n < segT; ++n) {
          float a = earr[n];
          const f16* hp = hf + (size_t)(s0 + n) * 96 + fo * 8;
          f16x4 v0 = *(const f16x4*)(hp);
          f16x4 v1 = *(const f16x4*)(hp + 4);
          r0 += a * (float)v0[0]; r1 += a * (float)v0[1];
          r2 += a * (float)v0[2]; r3 += a * (float)v0[3];
          r4 += a * (float)v1[0]; r5 += a * (float)v1[1];
          r6 += a * (float)v1[2]; r7 += a * (float)v1[3];
        }
      }
      f32x4 wa = {r0, r1, r2, r3}, wb = {r4, r5, r6, r7};
      *(f32x4*)(rpart + nc * 80 + fo * 8) = wa;
      *(f32x4*)(rpart + nc * 80 + fo * 8 + 4) = wb;
    }
    __syncthreads();
    // ---- P5: combine partials -> r into xcat (t<80) ----
    if (t < 80) {
      float S = red[0] + red[1] + red[2] + red[3];
      float invS = (S > 0.f) ? (1.f / S) : 0.f;
      float r = 0.f;
      #pragma unroll
      for (int ch = 0; ch < 19; ++ch) r += rpart[ch * 80 + t];
      if (t < 73) xcat[76 + t] = (f16)(r * invS);
    }
    __syncthreads();
  }
  // ---- output: out[b] = bout + hh . Wout ----
  if (t < 80) gatesv[t] = (t < 73) ? hhv[t] * Wout[t] : 0.f;
  __syncthreads();
  if (t == 0) {
    float a = bout[0];
    for (int i = 0; i < 73; ++i) a += gatesv[i];
    out[b] = a;
  }
}

// ---------------- workspace layout (bytes; ws_size = 256 MiB per harness fill) ----------------
#define OFF_H      0u          // float [8192][96]
#define OFF_G      3145728u    // f16 [2][8192][224] gate pre-activations
#define OFF_HF     17825792u   // f16 [8192][96]
#define OFF_AGGF   19398656u   // f16 [8192][96]
#define OFF_EHH    20971520u   // f16 [32768][80]
#define OFF_W2F    26214400u   // f16 [80][8192] fragment order, 16KB/kg (1.31 MB)
#define OFF_WIHT   27525120u   // f16 [224][96]
#define OFF_WHHT   27568128u   // f16 [224][96]
#define OFF_WCAT   27611136u   // f16 [292][232]
#define OFF_SEG    27746624u   // int [65]
#define OFF_CNT    27747072u   // int [8192]
#define OFF_BKT    27779840u   // int [8192][64]
#define OFF_M      29877248u   // f16 [32768][320] K-quarter partials (end ~50.8 MB)

extern "C" void kernel_launch(void* const* d_in, const int* in_sizes, int n_in,
                              void* d_out, int out_size, void* d_ws, size_t ws_size,
                              hipStream_t stream) {
  const float* nf   = (const float*)d_in[0];
  const float* ef   = (const float*)d_in[1];
  const float* W_in = (const float*)d_in[2];
  const float* b_in = (const float*)d_in[3];
  const float* W1   = (const float*)d_in[4];
  const float* b1   = (const float*)d_in[5];
  const float* W2   = (const float*)d_in[6];
  const float* b2   = (const float*)d_in[7];
  const float* gWih = (const float*)d_in[8];
  const float* gWhh = (const float*)d_in[9];
  const float* gbih = (const float*)d_in[10];
  const float* gbhh = (const float*)d_in[11];
  const float* lWih = (const float*)d_in[12];
  const float* lWhh = (const float*)d_in[13];
  const float* lbih = (const float*)d_in[14];
  const float* lbhh = (const float*)d_in[15];
  const float* Wout = (const float*)d_in[16];
  const float* bout = (const float*)d_in[17];
  const int* Esrc   = (const int*)d_in[18];
  const int* Etgt   = (const int*)d_in[19];
  const int* batch  = (const int*)d_in[20];

  char* ws = (char*)d_ws;
  float* h    = (float*)(ws + OFF_H);
  f16* G      = (f16*)(ws + OFF_G);
  f16* hf     = (f16*)(ws + OFF_HF);
  f16* aggf   = (f16*)(ws + OFF_AGGF);
  f16* ehh    = (f16*)(ws + OFF_EHH);
  f16* W2f    = (f16*)(ws + OFF_W2F);
  f16* WihT   = (f16*)(ws + OFF_WIHT);
  f16* WhhT   = (f16*)(ws + OFF_WHHT);
  f16* Wcat   = (f16*)(ws + OFF_WCAT);
  int* segst  = (int*)(ws + OFF_SEG);
  int* cnt    = (int*)(ws + OFF_CNT);
  int* bkt    = (int*)(ws + OFF_BKT);
  f16* m      = (f16*)(ws + OFF_M);

  hipMemsetAsync(cnt, 0, NN * sizeof(int), stream);
  prep_kernel<<<16433, 256, 0, stream>>>(nf, ef, W_in, b_in, W1, b1, W2, b2,
                                         gWih, gWhh, lWih, lWhh, batch, Etgt,
                                         h, hf, ehh, W2f, WihT, WhhT, Wcat,
                                         segst, cnt, bkt);
  for (int step = 0; step < 3; ++step) {
    vgemm_kernel<<<512, 256, 0, stream>>>(ehh, hf, W2f, Esrc, m);
    gather_kernel<<<2048, 384, 0, stream>>>(m, cnt, bkt, aggf);
    grugemm_kernel<<<128, 256, 0, stream>>>(aggf, hf, WihT, WhhT, G);
    gate_kernel<<<2336, 256, 0, stream>>>(G, gbih, gbhh, h, hf);
  }
  s2s_kernel<<<64, 512, 0, stream>>>(h, hf, Wcat, lbih, lbhh, Wout, bout, segst,
                                     (float*)d_out);
}

// Round 6
// 317.608 us; speedup vs baseline: 1.4895x; 1.0193x over previous
//
#include <hip/hip_runtime.h>

typedef _Float16 f16;
typedef f16 f16x2 __attribute__((ext_vector_type(2)));
typedef f16 f16x4 __attribute__((ext_vector_type(4)));
typedef f16 f16x8 __attribute__((ext_vector_type(8)));
typedef float f32x4 __attribute__((ext_vector_type(4)));

#define AS1 __attribute__((address_space(1)))
#define AS3 __attribute__((address_space(3)))

#define NN 8192
#define EE 32768

#if __has_builtin(__builtin_amdgcn_fdot2)
#define HAS_FDOT2 1
#else
#define HAS_FDOT2 0
#endif

__device__ __forceinline__ void glds16(const void* g, void* l) {
  __builtin_amdgcn_global_load_lds((const AS1 unsigned int*)g, (AS3 unsigned int*)l, 16, 0, 0);
}
// cooperative stage, 256 threads, 16B/lane; LDS base passed wave-uniform
__device__ __forceinline__ void stage_bytes(const void* g, void* s, int nbytes, int tid) {
  const int lane = tid & 63;
  for (int off = tid * 16; off < nbytes; off += 4096)
    glds16((const char*)g + off, (char*)s + (off - lane * 16));
}

// ---------------- prep: h0 GEMM, ehh, W2 fragment repack (pad 16KB/kg), weight casts, segstarts, CSR ----
__global__ void prep_kernel(
    const float* __restrict__ nf, const float* __restrict__ ef,
    const float* __restrict__ W_in, const float* __restrict__ b_in,
    const float* __restrict__ W1, const float* __restrict__ b1,
    const float* __restrict__ W2, const float* __restrict__ b2,
    const float* __restrict__ gWih, const float* __restrict__ gWhh,
    const float* __restrict__ lWih, const float* __restrict__ lWhh,
    const int* __restrict__ batch, const int* __restrict__ Etgt,
    float* __restrict__ h, f16* __restrict__ hf, f16* __restrict__ ehh,
    f16* __restrict__ W2f, f16* __restrict__ WihT, f16* __restrict__ WhhT,
    f16* __restrict__ Wcat, int* __restrict__ segstarts,
    int* __restrict__ count, int* __restrict__ bucket) {
  int t = blockIdx.x * 256 + threadIdx.x;
  if (t < 786432) {                       // h0: [8192][96] fp32+f16, pads zero
    int n = t / 96, i = t - n * 96;
    float v = 0.f;
    if (i < 73) {
      v = b_in[i];
      const float* nr = nf + n * 32;
      #pragma unroll
      for (int f = 0; f < 32; ++f) v += nr[f] * W_in[f * 73 + i];
    }
    h[t] = v; hf[t] = (f16)v;
    return;
  }
  t -= 786432;
  if (t < 2621440) {                      // ehh: [32768][80], col73 = 1.0 (bias), cols 74-79 zero
    int e = t / 80, k = t - e * 80;
    float v;
    if (k < 73) {
      v = b1[k];
      const float* er = ef + e * 16;
      #pragma unroll
      for (int f = 0; f < 16; ++f) v += er[f] * W1[f * 73 + k];
      v = fmaxf(v, 0.f);
    } else v = (k == 73) ? 1.f : 0.f;
    ehh[t] = (f16)v;
    return;
  }
  t -= 2621440;
  if (t < 655360) {                       // W2f: [80 kg][8192]: data [5 nt][3 ks][64 lane][8] + 512 pad
    int kg = t / 8192, r = t - kg * 8192;
    float v = 0.f;
    if (r < 7680) {
      int nt = r / 1536, r2 = r - nt * 1536;
      int ks = r2 / 512, r3 = r2 - ks * 512;
      int l = r3 >> 3, j = r3 & 7;
      int mr = l & 15, q = l >> 4;
      int i = nt * 16 + mr, jj = ks * 32 + q * 8 + j;
      if (i < 73 && jj < 73) {
        if (kg < 73) v = W2[kg * 5329 + i * 73 + jj];
        else if (kg == 73) v = b2[i * 73 + jj];
      }
    }
    W2f[t] = (f16)v;
    return;
  }
  t -= 655360;
  if (t < 43008) {                        // WihT/WhhT: [224][96]
    int half = t / 21504, r = t - half * 21504;
    int g = r / 96, k = r - g * 96;
    float v = 0.f;
    if (g < 219 && k < 73) v = half ? gWhh[g * 73 + k] : gWih[g * 73 + k];
    (half ? WhhT : WihT)[r] = (f16)v;
    return;
  }
  t -= 43008;
  if (t < 67744) {                        // Wcat[292][232]: q==hh fold -> [0..72]=wih_q+whh [76..148]=wih_r
    int g = t / 232, k = t - g * 232;
    float v = 0.f;
    if (k < 73) v = lWih[g * 146 + k] + lWhh[g * 73 + k];
    else if (k >= 76 && k < 149) v = lWih[g * 146 + (k - 3)];
    Wcat[t] = (f16)v;
    return;
  }
  t -= 67744;
  if (t < 65) {                           // segstarts: lower_bound(batch, t)
    int key = t, lo = 0, hi = NN;
    while (lo < hi) { int mid = (lo + hi) >> 1; if (batch[mid] < key) lo = mid + 1; else hi = mid; }
    segstarts[t] = lo;
    return;
  }
  t -= 65;
  if (t < EE) {                           // bucket fill: CSR-by-target (cap 64, lambda=4)
    int tg = Etgt[t];
    int slot = atomicAdd(&count[tg], 1);
    if (slot < 64) bucket[tg * 64 + slot] = t;
  }
}

// ---------------- edge-network matvec: m[e,i] = sum_{kg,j} ehh[e,kg] * hf[src[e],j] * W2[kg][i][j] ----
// v3: counted-vmcnt 3-buffer ring (T3/T4). 512 blocks (128 bm x 4 ksp), 256 edges/block,
// 4 m-tiles/wave (each ds_read_b128 feeds 4 MFMA -> MFMA-bound). Per iter EXACTLY 4 vmem ops
// (stage 16KB = 4 glds16/thread); ehh slice pre-staged to LDS so the vmcnt count is exact.
// stage(ch+1) -> s_waitcnt vmcnt(4) -> raw s_barrier: prefetch stays in flight across barriers.
__global__ __launch_bounds__(256, 2) void vgemm_kernel(
    const f16* __restrict__ ehh, const f16* __restrict__ hf,
    const f16* __restrict__ W2f, const int* __restrict__ Esrc,
    f16* __restrict__ m) {
  __shared__ __align__(16) f16 w2s[3][8192];     // 3 x 16 KB ring (write buf != both live read bufs)
  __shared__ __align__(16) f16 ehsl[256 * 20];   // ehh slice [row][20]
  const int tid = threadIdx.x;
  const int bm = blockIdx.x & 127, ksp = blockIdx.x >> 7;
  const int e0 = bm * 256;
  const int kg0 = ksp * 20;
  const int wave = tid >> 6, lane = tid & 63;
  const int q = lane >> 4, mr = lane & 15;

  // ehh slice -> LDS (row tid, 20 cols); 8B-aligned f16x4 ops
  {
    const f16* er = ehh + (size_t)(e0 + tid) * 80 + kg0;
    #pragma unroll
    for (int p = 0; p < 5; ++p)
      *(f16x4*)(ehsl + tid * 20 + p * 4) = *(const f16x4*)(er + p * 4);
  }
  // hf fragments in registers: wave owns 4 m-tiles (rows e0+wave*64+mt*16+mr)
  f16x8 hsv[4][3];
  #pragma unroll
  for (int mt = 0; mt < 4; ++mt) {
    int er = e0 + wave * 64 + mt * 16 + mr;
    int srcn = Esrc[er];
    #pragma unroll
    for (int ks = 0; ks < 3; ++ks)
      hsv[mt][ks] = *(const f16x8*)(hf + (size_t)srcn * 96 + ks * 32 + q * 8);
  }
  f32x4 zero = {0.f, 0.f, 0.f, 0.f};
  f32x4 acc[4][5];
  #pragma unroll
  for (int mt = 0; mt < 4; ++mt)
    #pragma unroll
    for (int nt = 0; nt < 5; ++nt) acc[mt][nt] = zero;

  __syncthreads();                 // ehsl visible; full drain -> clean vmcnt slate
  stage_bytes(W2f + (size_t)kg0 * 8192, w2s[0], 16384, tid);   // chunk 0: 4 loads/thread

  int rd = 0;
  for (int ch = 0; ch < 20; ++ch) {
    if (ch < 19) {
      int wr = rd + 1; if (wr == 3) wr = 0;
      stage_bytes(W2f + (size_t)(kg0 + ch + 1) * 8192, w2s[wr], 16384, tid);
      asm volatile("s_waitcnt vmcnt(4)" ::: "memory");   // chunk ch's 4 older loads done
    } else {
      asm volatile("s_waitcnt vmcnt(0)" ::: "memory");   // last chunk: full drain
    }
    __builtin_amdgcn_s_barrier();
    const f16* wb = w2s[rd];
    f16 ev[4];
    #pragma unroll
    for (int mt = 0; mt < 4; ++mt)
      ev[mt] = ehsl[(wave * 64 + mt * 16 + mr) * 20 + ch];
    f16x8 af[4][3];
    #pragma unroll
    for (int mt = 0; mt < 4; ++mt) {
      f16 e = ev[mt];
      f16x8 evv = {e, e, e, e, e, e, e, e};
      #pragma unroll
      for (int ks = 0; ks < 3; ++ks) af[mt][ks] = hsv[mt][ks] * evv;
    }
    __builtin_amdgcn_s_setprio(1);
    #pragma unroll
    for (int nt = 0; nt < 5; ++nt) {
      #pragma unroll
      for (int ks = 0; ks < 3; ++ks) {
        f16x8 bf = *(const f16x8*)(wb + (nt * 3 + ks) * 512 + lane * 8);  // conflict-free
        #pragma unroll
        for (int mt = 0; mt < 4; ++mt)
          acc[mt][nt] = __builtin_amdgcn_mfma_f32_16x16x32_f16(af[mt][ks], bf, acc[mt][nt], 0, 0, 0);
      }
    }
    __builtin_amdgcn_s_setprio(0);
    rd = rd + 1; if (rd == 3) rd = 0;
  }
  // epilogue: C layout col=lane&15, row=(lane>>4)*4+reg; f16 stores to disjoint quarter-row
  #pragma unroll
  for (int mt = 0; mt < 4; ++mt) {
    #pragma unroll
    for (int reg = 0; reg < 4; ++reg) {
      int er = e0 + wave * 64 + mt * 16 + q * 4 + reg;
      f16* mp = m + (size_t)er * 320 + ksp * 80;
      #pragma unroll
      for (int nt = 0; nt < 5; ++nt)
        mp[nt * 16 + mr] = (f16)acc[mt][nt][reg];
    }
  }
}

// ---------------- gather v2: vectorized quad loads. Thread (n, iq) owns features iq*4..iq*4+3 ----
// Per edge: 4 x f16x4 (8B) loads (one per K-quarter) instead of 16 scalar f16 loads -> 4.8x fewer
// load instructions, 16 independent loads in flight per thread. 768 blocks x 256 = 8192*24 threads.
__global__ void gather_kernel(const f16* __restrict__ m, const int* __restrict__ count,
                              const int* __restrict__ bucket, f16* __restrict__ aggf) {
  int t = blockIdx.x * 256 + threadIdx.x;  // exactly 8192*24
  int n = t / 24, iq = t - n * 24;
  f16x4 o = {(f16)0.f, (f16)0.f, (f16)0.f, (f16)0.f};
  if (iq < 20) {
    int cnt = count[n]; if (cnt > 64) cnt = 64;
    const int* bk = bucket + n * 64;
    float s0 = 0.f, s1 = 0.f, s2 = 0.f, s3 = 0.f;
    for (int j = 0; j < cnt; ++j) {
      const f16* mp = m + (size_t)bk[j] * 320 + iq * 4;
      f16x4 a = *(const f16x4*)(mp);
      f16x4 b = *(const f16x4*)(mp + 80);
      f16x4 c = *(const f16x4*)(mp + 160);
      f16x4 d = *(const f16x4*)(mp + 240);
      s0 += ((float)a[0] + (float)b[0]) + ((float)c[0] + (float)d[0]);
      s1 += ((float)a[1] + (float)b[1]) + ((float)c[1] + (float)d[1]);
      s2 += ((float)a[2] + (float)b[2]) + ((float)c[2] + (float)d[2]);
      s3 += ((float)a[3] + (float)b[3]) + ((float)c[3] + (float)d[3]);
    }
    o[0] = (f16)s0; o[1] = (f16)s1; o[2] = (f16)s2; o[3] = (f16)s3;
  }
  *(f16x4*)(aggf + (size_t)n * 96 + iq * 4) = o;   // cols 80..95 zeroed via iq 20..23
}

// ---------------- GRU gates GEMMs: G[0]=agg@WihT, G[1]=h@WhhT (G stored f16) ----------------
__global__ __launch_bounds__(256, 1) void grugemm_kernel(
    const f16* __restrict__ aggf, const f16* __restrict__ hf,
    const f16* __restrict__ WihT, const f16* __restrict__ WhhT,
    f16* __restrict__ G) {
  __shared__ __align__(16) f16 As[128 * 96];
  __shared__ __align__(16) f16 Bs[224 * 96];
  const int tid = threadIdx.x;
  const int bz = blockIdx.x >> 6, bm = blockIdx.x & 63;
  const int m0 = bm * 128;
  const f16* A = bz ? hf : aggf;
  const f16* B = bz ? WhhT : WihT;
  f16* out = G + bz * (NN * 224);
  stage_bytes(A + m0 * 96, As, 128 * 96 * 2, tid);
  stage_bytes(B, Bs, 224 * 96 * 2, tid);
  const int wave = tid >> 6, lane = tid & 63, q = lane >> 4, mr = lane & 15;
  __syncthreads();
  f16x8 af[2][3];
  #pragma unroll
  for (int mt = 0; mt < 2; ++mt)
    #pragma unroll
    for (int ks = 0; ks < 3; ++ks)
      af[mt][ks] = *(const f16x8*)(As + (wave * 32 + mt * 16 + mr) * 96 + ks * 32 + q * 8);
  f32x4 zero = {0.f, 0.f, 0.f, 0.f};
  f32x4 acc[2][14];
  #pragma unroll
  for (int mt = 0; mt < 2; ++mt)
    #pragma unroll
    for (int nt = 0; nt < 14; ++nt) acc[mt][nt] = zero;
  #pragma unroll
  for (int nt = 0; nt < 14; ++nt) {
    #pragma unroll
    for (int ks = 0; ks < 3; ++ks) {
      f16x8 bf = *(const f16x8*)(Bs + (nt * 16 + mr) * 96 + ks * 32 + q * 8);
      #pragma unroll
      for (int mt = 0; mt < 2; ++mt)
        acc[mt][nt] = __builtin_amdgcn_mfma_f32_16x16x32_f16(af[mt][ks], bf, acc[mt][nt], 0, 0, 0);
    }
  }
  #pragma unroll
  for (int mt = 0; mt < 2; ++mt)
    #pragma unroll
    for (int reg = 0; reg < 4; ++reg) {
      int row = m0 + wave * 32 + mt * 16 + q * 4 + reg;
      #pragma unroll
      for (int nt = 0; nt < 14; ++nt)
        out[row * 224 + nt * 16 + mr] = (f16)acc[mt][nt][reg];
    }
}

// ---------------- GRU elementwise update (G in f16) ----------------
__global__ void gate_kernel(const f16* __restrict__ G, const float* __restrict__ bih,
                            const float* __restrict__ bhh, float* __restrict__ h,
                            f16* __restrict__ hf) {
  int idx = blockIdx.x * 256 + threadIdx.x;  // exactly 8192*73
  int n = idx / 73, i = idx - n * 73;
  const f16* g0 = G + n * 224;
  const f16* g1 = G + NN * 224 + n * 224;
  float rr = (float)g0[i] + bih[i] + (float)g1[i] + bhh[i];
  rr = 1.f / (1.f + __expf(-rr));
  float zz = (float)g0[73 + i] + bih[73 + i] + (float)g1[73 + i] + bhh[73 + i];
  zz = 1.f / (1.f + __expf(-zz));
  float nx = (float)g0[146 + i] + bih[146 + i] + rr * ((float)g1[146 + i] + bhh[146 + i]);
  float nn_ = 2.f / (1.f + __expf(-2.f * nx)) - 1.f;
  float hv = h[n * 96 + i];
  float hn = (1.f - zz) * nn_ + zz * hv;
  h[n * 96 + i] = hn;
  hf[n * 96 + i] = (f16)hn;
}

// ---------------- Set2Set helpers ----------------
__device__ __forceinline__ float wred_sum(float v) {
  #pragma unroll
  for (int off = 32; off; off >>= 1) v += __shfl_xor(v, off, 64);
  return v;
}
// fp32-accumulating f16 dots (v_dot2_f32_f16)
__device__ __forceinline__ float dot8(f16x8 w, f16x8 x, float acc) {
#if HAS_FDOT2
  acc = __builtin_amdgcn_fdot2((f16x2)__builtin_shufflevector(w, w, 0, 1),
                               (f16x2)__builtin_shufflevector(x, x, 0, 1), acc, false);
  acc = __builtin_amdgcn_fdot2((f16x2)__builtin_shufflevector(w, w, 2, 3),
                               (f16x2)__builtin_shufflevector(x, x, 2, 3), acc, false);
  acc = __builtin_amdgcn_fdot2((f16x2)__builtin_shufflevector(w, w, 4, 5),
                               (f16x2)__builtin_shufflevector(x, x, 4, 5), acc, false);
  acc = __builtin_amdgcn_fdot2((f16x2)__builtin_shufflevector(w, w, 6, 7),
                               (f16x2)__builtin_shufflevector(x, x, 6, 7), acc, false);
#else
  #pragma unroll
  for (int e = 0; e < 8; ++e) acc += (float)w[e] * (float)x[e];
#endif
  return acc;
}
__device__ __forceinline__ float dot4(f16x4 w, f16x4 x, float acc) {
#if HAS_FDOT2
  acc = __builtin_amdgcn_fdot2((f16x2)__builtin_shufflevector(w, w, 0, 1),
                               (f16x2)__builtin_shufflevector(x, x, 0, 1), acc, false);
  acc = __builtin_amdgcn_fdot2((f16x2)__builtin_shufflevector(w, w, 2, 3),
                               (f16x2)__builtin_shufflevector(x, x, 2, 3), acc, false);
#else
  #pragma unroll
  for (int e = 0; e < 4; ++e) acc += (float)w[e] * (float)x[e];
#endif
  return acc;
}

#define S2SCAP 256   // absolute per-segment cap (binomial mean 128, sd 11)
#define NCAP 190     // rows cached in LDS; [NCAP,segT) via global fallback (normally empty)

// ---------------- Set2Set v9: + register-pinned hseg rows (P3) and blocks (P4) ----------
__global__ __launch_bounds__(512, 2) void s2s_kernel(
    const float* __restrict__ h, const f16* __restrict__ hf,
    const f16* __restrict__ Wcat,
    const float* __restrict__ lbih, const float* __restrict__ lbhh,
    const float* __restrict__ Wout, const float* __restrict__ bout,
    const int* __restrict__ segstarts, float* __restrict__ out) {
  __shared__ __align__(16) f16 hseg[NCAP * 84];   // 31920 B, row stride 84 f16 (b64-aligned)
  __shared__ __align__(16) f16 xcat[240];
  __shared__ float hhv[80];
  __shared__ float gatesv[292];
  __shared__ float earr[S2SCAP];
  __shared__ float red[4];
  __shared__ __align__(16) float rpart[19 * 80];
  const int t = threadIdx.x, b = blockIdx.x;
  const int wid = t >> 6, lane = t & 63;

  const int s0 = segstarts[b];
  int segT = segstarts[b + 1] - s0;
  if (segT > S2SCAP) segT = S2SCAP;
  const int c = segT < NCAP ? segT : NCAP;

  if (t < 240) xcat[t] = (f16)0.f;
  if (t < 80) hhv[t] = 0.f;
  if (t < S2SCAP) earr[t] = 0.f;   // pre-zero so P4 runs unguarded

  // stage hseg rows (f16, cols 0..75 data incl. zero pads 73..75; cols 76..83 zeroed);
  // rows [c, NCAP) fully zeroed so P4 needs no per-row guard (0*0 contributions)
  for (int r = wid; r < NCAP; r += 8) {
    if (lane < 21) {
      f16x4 v = {(f16)0.f, (f16)0.f, (f16)0.f, (f16)0.f};
      if (r < c && lane < 19)
        v = *(const f16x4*)(hf + (size_t)(s0 + r) * 96 + lane * 4);
      *(f16x4*)(hseg + r * 84 + lane * 4) = v;
    }
  }

  const bool isg = (t >= 220);
  const int g2 = t - 220;
  float bias = 0.f;
  if (isg) bias = lbih[g2] + lbhh[g2];
  // Folded LSTM weight row RESIDENT in registers (q==hh: Wcat[0..72]=wih_q+whh, [76..148]=wih_r)
  f16x8 wihF[19];
  {
    const f16* wr = Wcat + (size_t)(isg ? g2 : 0) * 232;
    #pragma unroll
    for (int v = 0; v < 19; ++v) wihF[v] = *(const f16x8*)(wr + v * 8);
  }
  const int nc = t / 10, fo = t - nc * 10;    // readout mapping (t<190)
  float creg = 0.f;                            // LSTM cell state (t<73)
  __syncthreads();                             // hseg staged & visible

  // ---- register pinning (loop-invariant LDS reads, clamped for inactive threads) ----
  f16x4 hrow[19];                              // P3: own hseg row (t<190; rows>=c are zero)
  {
    const f16* hp = hseg + (t < NCAP ? t : 0) * 84;
    #pragma unroll
    for (int k = 0; k < 19; ++k) hrow[k] = *(const f16x4*)(hp + k * 4);
  }
  f16x4 hb0[10], hb1[10];                      // P4: 10-node block at feature-octet fo
  {
    int ncc = (t < 190) ? nc : 0, foc = (t < 190) ? fo : 0;
    #pragma unroll
    for (int j = 0; j < 10; ++j) {
      const f16* hp = hseg + (ncc * 10 + j) * 84 + foc * 8;
      hb0[j] = *(const f16x4*)(hp);
      hb1[j] = *(const f16x4*)(hp + 4);
    }
  }

  for (int iter = 0; iter < 12; ++iter) {
    // ---- P1: LSTM gate matvec (292 threads), folded K=152, 4 accumulators ----
    if (isg) {
      float a0 = bias, a1 = 0.f, a2 = 0.f, a3 = 0.f;
      #pragma unroll
      for (int v = 0; v < 19; ++v) {
        f16x8 x = *(const f16x8*)(xcat + v * 8);
        int sel = v & 3;
        if (sel == 0) a0 = dot8(wihF[v], x, a0);
        else if (sel == 1) a1 = dot8(wihF[v], x, a1);
        else if (sel == 2) a2 = dot8(wihF[v], x, a2);
        else a3 = dot8(wihF[v], x, a3);
      }
      gatesv[g2] = (a0 + a1) + (a2 + a3);
    }
    __syncthreads();
    // ---- P2: LSTM elementwise update (t<73) ----
    if (t < 73) {
      float ig = 1.f / (1.f + __expf(-gatesv[t]));
      float fg = 1.f / (1.f + __expf(-gatesv[73 + t]));
      float gx = gatesv[146 + t];
      float gg = 2.f / (1.f + __expf(-2.f * gx)) - 1.f;
      float og = 1.f / (1.f + __expf(-gatesv[219 + t]));
      creg = fg * creg + ig * gg;
      float cth = 2.f / (1.f + __expf(-2.f * creg)) - 1.f;
      float hh = og * cth;
      hhv[t] = hh;
      xcat[t] = (f16)hh;        // q slot (doubles as hh via folded weights)
    }
    __syncthreads();
    // ---- P3: logits + exp + per-wave sums (t<192; hseg row from REGISTERS) ----
    if (wid < 3) {
      float a = 0.f;
      if (t < c) {
        float e0 = 0.f, e1 = 0.f;
        #pragma unroll
        for (int k = 0; k < 19; ++k) {
          f16x4 xk = *(const f16x4*)(xcat + k * 4);
          if (k & 1) e1 = dot4(hrow[k], xk, e1);
          else e0 = dot4(hrow[k], xk, e0);
        }
        a = __expf(fminf(e0 + e1, 80.f));  // logits bounded; no max-sub in fp32
        earr[t] = a;
      }
      float ws = wred_sum(a);
      if (lane == 0) red[wid] = ws;
    }
    // fallback logits for nodes >= NCAP (normally zero-trip)
    if (wid == 0) {
      float fa = 0.f;
      int n = NCAP + lane;
      if (n < segT) {
        const float* hr = h + (size_t)(s0 + n) * 96;
        float e = 0.f;
        for (int i = 0; i < 73; ++i) e += hr[i] * hhv[i];
        fa = __expf(fminf(e, 80.f));
        earr[n] = fa;
      }
      float ws2 = wred_sum(fa);
      if (lane == 0) red[3] = ws2;
    }
    __syncthreads();
    // ---- P4: weighted readout partials (hseg block from REGISTERS; earr zero-padded) ----
    if (t < 190) {
      float r0 = 0.f, r1 = 0.f, r2 = 0.f, r3 = 0.f, r4 = 0.f, r5 = 0.f, r6 = 0.f, r7 = 0.f;
      #pragma unroll
      for (int j = 0; j < 10; ++j) {
        float a = earr[nc * 10 + j];
        r0 += a * (float)hb0[j][0]; r1 += a * (float)hb0[j][1];
        r2 += a * (float)hb0[j][2]; r3 += a * (float)hb0[j][3];
        r4 += a * (float)hb1[j][0]; r5 += a * (float)hb1[j][1];
        r6 += a * (float)hb1[j][2]; r7 += a * (float)hb1[j][3];
      }
      if (nc == 18) {  // fallback nodes from global hf (normally zero-trip)
        for (int n = NCAP; n < segT; ++n) {
          float a = earr[n];
          const f16* hp = hf + (size_t)(s0 + n) * 96 + fo * 8;
          f16x4 v0 = *(const f16x4*)(hp);
          f16x4 v1 = *(const f16x4*)(hp + 4);
          r0 += a * (float)v0[0]; r1 += a * (float)v0[1];
          r2 += a * (float)v0[2]; r3 += a * (float)v0[3];
          r4 += a * (float)v1[0]; r5 += a * (float)v1[1];
          r6 += a * (float)v1[2]; r7 += a * (float)v1[3];
        }
      }
      f32x4 wa = {r0, r1, r2, r3}, wb = {r4, r5, r6, r7};
      *(f32x4*)(rpart + nc * 80 + fo * 8) = wa;
      *(f32x4*)(rpart + nc * 80 + fo * 8 + 4) = wb;
    }
    __syncthreads();
    // ---- P5: combine partials -> r into xcat (t<80) ----
    if (t < 80) {
      float S = red[0] + red[1] + red[2] + red[3];
      float invS = (S > 0.f) ? (1.f / S) : 0.f;
      float r = 0.f;
      #pragma unroll
      for (int ch = 0; ch < 19; ++ch) r += rpart[ch * 80 + t];
      if (t < 73) xcat[76 + t] = (f16)(r * invS);
    }
    __syncthreads();
  }
  // ---- output: out[b] = bout + hh . Wout ----
  if (t < 80) gatesv[t] = (t < 73) ? hhv[t] * Wout[t] : 0.f;
  __syncthreads();
  if (t == 0) {
    float a = bout[0];
    for (int i = 0; i < 73; ++i) a += gatesv[i];
    out[b] = a;
  }
}

// ---------------- workspace layout (bytes; ws_size = 256 MiB per harness fill) ----------------
#define OFF_H      0u          // float [8192][96]
#define OFF_G      3145728u    // f16 [2][8192][224] gate pre-activations
#define OFF_HF     17825792u   // f16 [8192][96]
#define OFF_AGGF   19398656u   // f16 [8192][96]
#define OFF_EHH    20971520u   // f16 [32768][80]
#define OFF_W2F    26214400u   // f16 [80][8192] fragment order, 16KB/kg (1.31 MB)
#define OFF_WIHT   27525120u   // f16 [224][96]
#define OFF_WHHT   27568128u   // f16 [224][96]
#define OFF_WCAT   27611136u   // f16 [292][232]
#define OFF_SEG    27746624u   // int [65]
#define OFF_CNT    27747072u   // int [8192]
#define OFF_BKT    27779840u   // int [8192][64]
#define OFF_M      29877248u   // f16 [32768][320] K-quarter partials (end ~50.8 MB)

extern "C" void kernel_launch(void* const* d_in, const int* in_sizes, int n_in,
                              void* d_out, int out_size, void* d_ws, size_t ws_size,
                              hipStream_t stream) {
  const float* nf   = (const float*)d_in[0];
  const float* ef   = (const float*)d_in[1];
  const float* W_in = (const float*)d_in[2];
  const float* b_in = (const float*)d_in[3];
  const float* W1   = (const float*)d_in[4];
  const float* b1   = (const float*)d_in[5];
  const float* W2   = (const float*)d_in[6];
  const float* b2   = (const float*)d_in[7];
  const float* gWih = (const float*)d_in[8];
  const float* gWhh = (const float*)d_in[9];
  const float* gbih = (const float*)d_in[10];
  const float* gbhh = (const float*)d_in[11];
  const float* lWih = (const float*)d_in[12];
  const float* lWhh = (const float*)d_in[13];
  const float* lbih = (const float*)d_in[14];
  const float* lbhh = (const float*)d_in[15];
  const float* Wout = (const float*)d_in[16];
  const float* bout = (const float*)d_in[17];
  const int* Esrc   = (const int*)d_in[18];
  const int* Etgt   = (const int*)d_in[19];
  const int* batch  = (const int*)d_in[20];

  char* ws = (char*)d_ws;
  float* h    = (float*)(ws + OFF_H);
  f16* G      = (f16*)(ws + OFF_G);
  f16* hf     = (f16*)(ws + OFF_HF);
  f16* aggf   = (f16*)(ws + OFF_AGGF);
  f16* ehh    = (f16*)(ws + OFF_EHH);
  f16* W2f    = (f16*)(ws + OFF_W2F);
  f16* WihT   = (f16*)(ws + OFF_WIHT);
  f16* WhhT   = (f16*)(ws + OFF_WHHT);
  f16* Wcat   = (f16*)(ws + OFF_WCAT);
  int* segst  = (int*)(ws + OFF_SEG);
  int* cnt    = (int*)(ws + OFF_CNT);
  int* bkt    = (int*)(ws + OFF_BKT);
  f16* m      = (f16*)(ws + OFF_M);

  hipMemsetAsync(cnt, 0, NN * sizeof(int), stream);
  prep_kernel<<<16433, 256, 0, stream>>>(nf, ef, W_in, b_in, W1, b1, W2, b2,
                                         gWih, gWhh, lWih, lWhh, batch, Etgt,
                                         h, hf, ehh, W2f, WihT, WhhT, Wcat,
                                         segst, cnt, bkt);
  for (int step = 0; step < 3; ++step) {
    vgemm_kernel<<<512, 256, 0, stream>>>(ehh, hf, W2f, Esrc, m);
    gather_kernel<<<768, 256, 0, stream>>>(m, cnt, bkt, aggf);
    grugemm_kernel<<<128, 256, 0, stream>>>(aggf, hf, WihT, WhhT, G);
    gate_kernel<<<2336, 256, 0, stream>>>(G, gbih, gbhh, h, hf);
  }
  s2s_kernel<<<64, 512, 0, stream>>>(h, hf, Wcat, lbih, lbhh, Wout, bout, segst,
                                     (float*)d_out);
}

// Round 7
// 314.080 us; speedup vs baseline: 1.5062x; 1.0112x over previous
//
#include <hip/hip_runtime.h>

typedef _Float16 f16;
typedef f16 f16x2 __attribute__((ext_vector_type(2)));
typedef f16 f16x4 __attribute__((ext_vector_type(4)));
typedef f16 f16x8 __attribute__((ext_vector_type(8)));
typedef float f32x4 __attribute__((ext_vector_type(4)));

#define AS1 __attribute__((address_space(1)))
#define AS3 __attribute__((address_space(3)))

#define NN 8192
#define EE 32768

#if __has_builtin(__builtin_amdgcn_fdot2)
#define HAS_FDOT2 1
#else
#define HAS_FDOT2 0
#endif

__device__ __forceinline__ void glds16(const void* g, void* l) {
  __builtin_amdgcn_global_load_lds((const AS1 unsigned int*)g, (AS3 unsigned int*)l, 16, 0, 0);
}
// cooperative stage, 256 threads, 16B/lane; LDS base passed wave-uniform
__device__ __forceinline__ void stage_bytes(const void* g, void* s, int nbytes, int tid) {
  const int lane = tid & 63;
  for (int off = tid * 16; off < nbytes; off += 4096)
    glds16((const char*)g + off, (char*)s + (off - lane * 16));
}

// ---------------- prep: h0 GEMM, ehh, W2 fragment repack (76 kg, 16KB/kg), weight casts, segstarts, CSR ----
__global__ void prep_kernel(
    const float* __restrict__ nf, const float* __restrict__ ef,
    const float* __restrict__ W_in, const float* __restrict__ b_in,
    const float* __restrict__ W1, const float* __restrict__ b1,
    const float* __restrict__ W2, const float* __restrict__ b2,
    const float* __restrict__ gWih, const float* __restrict__ gWhh,
    const float* __restrict__ lWih, const float* __restrict__ lWhh,
    const int* __restrict__ batch, const int* __restrict__ Etgt,
    float* __restrict__ h, f16* __restrict__ hf, f16* __restrict__ ehh,
    f16* __restrict__ W2f, f16* __restrict__ WihT, f16* __restrict__ WhhT,
    f16* __restrict__ Wcat, int* __restrict__ segstarts,
    int* __restrict__ count, int* __restrict__ bucket) {
  int t = blockIdx.x * 256 + threadIdx.x;
  if (t < 786432) {                       // h0: [8192][96] fp32+f16, pads zero
    int n = t / 96, i = t - n * 96;
    float v = 0.f;
    if (i < 73) {
      v = b_in[i];
      const float* nr = nf + n * 32;
      #pragma unroll
      for (int f = 0; f < 32; ++f) v += nr[f] * W_in[f * 73 + i];
    }
    h[t] = v; hf[t] = (f16)v;
    return;
  }
  t -= 786432;
  if (t < 2621440) {                      // ehh: [32768][80], col73 = 1.0 (bias), cols 74-79 zero
    int e = t / 80, k = t - e * 80;
    float v;
    if (k < 73) {
      v = b1[k];
      const float* er = ef + e * 16;
      #pragma unroll
      for (int f = 0; f < 16; ++f) v += er[f] * W1[f * 73 + k];
      v = fmaxf(v, 0.f);
    } else v = (k == 73) ? 1.f : 0.f;
    ehh[t] = (f16)v;
    return;
  }
  t -= 2621440;
  if (t < 622592) {                       // W2f: [76 kg][8192]: data [5 nt][3 ks][64 lane][8] + 512 pad
    int kg = t / 8192, r = t - kg * 8192;
    float v = 0.f;
    if (r < 7680) {
      int nt = r / 1536, r2 = r - nt * 1536;
      int ks = r2 / 512, r3 = r2 - ks * 512;
      int l = r3 >> 3, j = r3 & 7;
      int mr = l & 15, q = l >> 4;
      int i = nt * 16 + mr, jj = ks * 32 + q * 8 + j;
      if (i < 73 && jj < 73) {
        if (kg < 73) v = W2[kg * 5329 + i * 73 + jj];
        else if (kg == 73) v = b2[i * 73 + jj];
      }
    }
    W2f[t] = (f16)v;
    return;
  }
  t -= 622592;
  if (t < 43008) {                        // WihT/WhhT: [224][96]
    int half = t / 21504, r = t - half * 21504;
    int g = r / 96, k = r - g * 96;
    float v = 0.f;
    if (g < 219 && k < 73) v = half ? gWhh[g * 73 + k] : gWih[g * 73 + k];
    (half ? WhhT : WihT)[r] = (f16)v;
    return;
  }
  t -= 43008;
  if (t < 67744) {                        // Wcat[292][232]: q==hh fold -> [0..72]=wih_q+whh [76..148]=wih_r
    int g = t / 232, k = t - g * 232;
    float v = 0.f;
    if (k < 73) v = lWih[g * 146 + k] + lWhh[g * 73 + k];
    else if (k >= 76 && k < 149) v = lWih[g * 146 + (k - 3)];
    Wcat[t] = (f16)v;
    return;
  }
  t -= 67744;
  if (t < 65) {                           // segstarts: lower_bound(batch, t)
    int key = t, lo = 0, hi = NN;
    while (lo < hi) { int mid = (lo + hi) >> 1; if (batch[mid] < key) lo = mid + 1; else hi = mid; }
    segstarts[t] = lo;
    return;
  }
  t -= 65;
  if (t < EE) {                           // bucket fill: CSR-by-target (cap 64, lambda=4)
    int tg = Etgt[t];
    int slot = atomicAdd(&count[tg], 1);
    if (slot < 64) bucket[tg * 64 + slot] = t;
  }
}

// ---------------- edge-network matvec: m[e,i] = sum_{kg,j} ehh[e,kg] * hf[src[e],j] * W2[kg][i][j] ----
// v4: 19-kg quarters (76 total vs 80: -5% MFMA+stage) + ev-prefetch (next chunk's ehsl reads hoisted
// before the wait/barrier -> post-barrier path is VALU-only). Counted-vmcnt 3-buffer ring (T3/T4):
// per iter exactly 4 vmem ops; stage(ch+1) -> s_waitcnt vmcnt(4) -> s_barrier; prefetch stays in
// flight across barriers, drained to 0 only on the last chunk.
__global__ __launch_bounds__(256, 2) void vgemm_kernel(
    const f16* __restrict__ ehh, const f16* __restrict__ hf,
    const f16* __restrict__ W2f, const int* __restrict__ Esrc,
    f16* __restrict__ m) {
  __shared__ __align__(16) f16 w2s[3][8192];     // 3 x 16 KB ring (write buf never a live read buf)
  __shared__ __align__(16) f16 ehsl[256 * 20];   // ehh slice [row][20] (19 used + 1 pad)
  const int tid = threadIdx.x;
  const int bm = blockIdx.x & 127, ksp = blockIdx.x >> 7;
  const int e0 = bm * 256;
  const int kg0 = ksp * 19;
  const int wave = tid >> 6, lane = tid & 63;
  const int q = lane >> 4, mr = lane & 15;

  // ehh slice -> LDS (row tid, cols kg0..kg0+20); max kg0=57 -> reads cols 57..76 < 80, in-bounds
  {
    const f16* er = ehh + (size_t)(e0 + tid) * 80 + kg0;
    #pragma unroll
    for (int p = 0; p < 5; ++p)
      *(f16x4*)(ehsl + tid * 20 + p * 4) = *(const f16x4*)(er + p * 4);
  }
  // hf fragments in registers: wave owns 4 m-tiles (rows e0+wave*64+mt*16+mr)
  f16x8 hsv[4][3];
  #pragma unroll
  for (int mt = 0; mt < 4; ++mt) {
    int er = e0 + wave * 64 + mt * 16 + mr;
    int srcn = Esrc[er];
    #pragma unroll
    for (int ks = 0; ks < 3; ++ks)
      hsv[mt][ks] = *(const f16x8*)(hf + (size_t)srcn * 96 + ks * 32 + q * 8);
  }
  f32x4 zero = {0.f, 0.f, 0.f, 0.f};
  f32x4 acc[4][5];
  #pragma unroll
  for (int mt = 0; mt < 4; ++mt)
    #pragma unroll
    for (int nt = 0; nt < 5; ++nt) acc[mt][nt] = zero;

  __syncthreads();                 // ehsl visible; full drain -> clean vmcnt slate
  stage_bytes(W2f + (size_t)kg0 * 8192, w2s[0], 16384, tid);   // chunk 0: 4 loads/thread

  const int erow = wave * 64 + mr;  // ehsl row base (mt adds 16 each)
  f16 evc[4];                       // current chunk's ev values (prefetched)
  #pragma unroll
  for (int mt = 0; mt < 4; ++mt) evc[mt] = ehsl[(erow + mt * 16) * 20 + 0];

  int rd = 0;
  for (int ch = 0; ch < 19; ++ch) {
    f16 evn[4];
    if (ch < 18) {
      int wr = rd + 1; if (wr == 3) wr = 0;
      stage_bytes(W2f + (size_t)(kg0 + ch + 1) * 8192, w2s[wr], 16384, tid);
      // prefetch next chunk's ev while this chunk's loads drain (LDS latency hidden here)
      #pragma unroll
      for (int mt = 0; mt < 4; ++mt) evn[mt] = ehsl[(erow + mt * 16) * 20 + ch + 1];
      asm volatile("s_waitcnt vmcnt(4)" ::: "memory");   // chunk ch's 4 older loads done
    } else {
      asm volatile("s_waitcnt vmcnt(0)" ::: "memory");   // last chunk: full drain
    }
    __builtin_amdgcn_s_barrier();
    const f16* wb = w2s[rd];
    f16x8 af[4][3];
    #pragma unroll
    for (int mt = 0; mt < 4; ++mt) {
      f16 e = evc[mt];
      f16x8 evv = {e, e, e, e, e, e, e, e};
      #pragma unroll
      for (int ks = 0; ks < 3; ++ks) af[mt][ks] = hsv[mt][ks] * evv;
    }
    __builtin_amdgcn_s_setprio(1);
    #pragma unroll
    for (int nt = 0; nt < 5; ++nt) {
      #pragma unroll
      for (int ks = 0; ks < 3; ++ks) {
        f16x8 bf = *(const f16x8*)(wb + (nt * 3 + ks) * 512 + lane * 8);  // conflict-free
        #pragma unroll
        for (int mt = 0; mt < 4; ++mt)
          acc[mt][nt] = __builtin_amdgcn_mfma_f32_16x16x32_f16(af[mt][ks], bf, acc[mt][nt], 0, 0, 0);
      }
    }
    __builtin_amdgcn_s_setprio(0);
    #pragma unroll
    for (int mt = 0; mt < 4; ++mt) evc[mt] = evn[mt];
    rd = rd + 1; if (rd == 3) rd = 0;
  }
  // epilogue: C layout col=lane&15, row=(lane>>4)*4+reg; f16 stores to disjoint quarter-row
  #pragma unroll
  for (int mt = 0; mt < 4; ++mt) {
    #pragma unroll
    for (int reg = 0; reg < 4; ++reg) {
      int er = e0 + wave * 64 + mt * 16 + q * 4 + reg;
      f16* mp = m + (size_t)er * 320 + ksp * 80;
      #pragma unroll
      for (int nt = 0; nt < 5; ++nt)
        mp[nt * 16 + mr] = (f16)acc[mt][nt][reg];
    }
  }
}

// ---------------- gather v2: vectorized quad loads. Thread (n, iq) owns features iq*4..iq*4+3 ----
__global__ void gather_kernel(const f16* __restrict__ m, const int* __restrict__ count,
                              const int* __restrict__ bucket, f16* __restrict__ aggf) {
  int t = blockIdx.x * 256 + threadIdx.x;  // exactly 8192*24
  int n = t / 24, iq = t - n * 24;
  f16x4 o = {(f16)0.f, (f16)0.f, (f16)0.f, (f16)0.f};
  if (iq < 20) {
    int cnt = count[n]; if (cnt > 64) cnt = 64;
    const int* bk = bucket + n * 64;
    float s0 = 0.f, s1 = 0.f, s2 = 0.f, s3 = 0.f;
    for (int j = 0; j < cnt; ++j) {
      const f16* mp = m + (size_t)bk[j] * 320 + iq * 4;
      f16x4 a = *(const f16x4*)(mp);
      f16x4 b = *(const f16x4*)(mp + 80);
      f16x4 c = *(const f16x4*)(mp + 160);
      f16x4 d = *(const f16x4*)(mp + 240);
      s0 += ((float)a[0] + (float)b[0]) + ((float)c[0] + (float)d[0]);
      s1 += ((float)a[1] + (float)b[1]) + ((float)c[1] + (float)d[1]);
      s2 += ((float)a[2] + (float)b[2]) + ((float)c[2] + (float)d[2]);
      s3 += ((float)a[3] + (float)b[3]) + ((float)c[3] + (float)d[3]);
    }
    o[0] = (f16)s0; o[1] = (f16)s1; o[2] = (f16)s2; o[3] = (f16)s3;
  }
  *(f16x4*)(aggf + (size_t)n * 96 + iq * 4) = o;   // cols 80..95 zeroed via iq 20..23
}

// ---------------- GRU gates GEMMs: G[0]=agg@WihT, G[1]=h@WhhT (G stored f16) ----------------
__global__ __launch_bounds__(256, 1) void grugemm_kernel(
    const f16* __restrict__ aggf, const f16* __restrict__ hf,
    const f16* __restrict__ WihT, const f16* __restrict__ WhhT,
    f16* __restrict__ G) {
  __shared__ __align__(16) f16 As[128 * 96];
  __shared__ __align__(16) f16 Bs[224 * 96];
  const int tid = threadIdx.x;
  const int bz = blockIdx.x >> 6, bm = blockIdx.x & 63;
  const int m0 = bm * 128;
  const f16* A = bz ? hf : aggf;
  const f16* B = bz ? WhhT : WihT;
  f16* out = G + bz * (NN * 224);
  stage_bytes(A + m0 * 96, As, 128 * 96 * 2, tid);
  stage_bytes(B, Bs, 224 * 96 * 2, tid);
  const int wave = tid >> 6, lane = tid & 63, q = lane >> 4, mr = lane & 15;
  __syncthreads();
  f16x8 af[2][3];
  #pragma unroll
  for (int mt = 0; mt < 2; ++mt)
    #pragma unroll
    for (int ks = 0; ks < 3; ++ks)
      af[mt][ks] = *(const f16x8*)(As + (wave * 32 + mt * 16 + mr) * 96 + ks * 32 + q * 8);
  f32x4 zero = {0.f, 0.f, 0.f, 0.f};
  f32x4 acc[2][14];
  #pragma unroll
  for (int mt = 0; mt < 2; ++mt)
    #pragma unroll
    for (int nt = 0; nt < 14; ++nt) acc[mt][nt] = zero;
  #pragma unroll
  for (int nt = 0; nt < 14; ++nt) {
    #pragma unroll
    for (int ks = 0; ks < 3; ++ks) {
      f16x8 bf = *(const f16x8*)(Bs + (nt * 16 + mr) * 96 + ks * 32 + q * 8);
      #pragma unroll
      for (int mt = 0; mt < 2; ++mt)
        acc[mt][nt] = __builtin_amdgcn_mfma_f32_16x16x32_f16(af[mt][ks], bf, acc[mt][nt], 0, 0, 0);
    }
  }
  #pragma unroll
  for (int mt = 0; mt < 2; ++mt)
    #pragma unroll
    for (int reg = 0; reg < 4; ++reg) {
      int row = m0 + wave * 32 + mt * 16 + q * 4 + reg;
      #pragma unroll
      for (int nt = 0; nt < 14; ++nt)
        out[row * 224 + nt * 16 + mr] = (f16)acc[mt][nt][reg];
    }
}

// ---------------- GRU elementwise update (G in f16) ----------------
__global__ void gate_kernel(const f16* __restrict__ G, const float* __restrict__ bih,
                            const float* __restrict__ bhh, float* __restrict__ h,
                            f16* __restrict__ hf) {
  int idx = blockIdx.x * 256 + threadIdx.x;  // exactly 8192*73
  int n = idx / 73, i = idx - n * 73;
  const f16* g0 = G + n * 224;
  const f16* g1 = G + NN * 224 + n * 224;
  float rr = (float)g0[i] + bih[i] + (float)g1[i] + bhh[i];
  rr = 1.f / (1.f + __expf(-rr));
  float zz = (float)g0[73 + i] + bih[73 + i] + (float)g1[73 + i] + bhh[73 + i];
  zz = 1.f / (1.f + __expf(-zz));
  float nx = (float)g0[146 + i] + bih[146 + i] + rr * ((float)g1[146 + i] + bhh[146 + i]);
  float nn_ = 2.f / (1.f + __expf(-2.f * nx)) - 1.f;
  float hv = h[n * 96 + i];
  float hn = (1.f - zz) * nn_ + zz * hv;
  h[n * 96 + i] = hn;
  hf[n * 96 + i] = (f16)hn;
}

// ---------------- Set2Set helpers ----------------
__device__ __forceinline__ float wred_sum(float v) {
  #pragma unroll
  for (int off = 32; off; off >>= 1) v += __shfl_xor(v, off, 64);
  return v;
}
// fp32-accumulating f16 dots (v_dot2_f32_f16)
__device__ __forceinline__ float dot8(f16x8 w, f16x8 x, float acc) {
#if HAS_FDOT2
  acc = __builtin_amdgcn_fdot2((f16x2)__builtin_shufflevector(w, w, 0, 1),
                               (f16x2)__builtin_shufflevector(x, x, 0, 1), acc, false);
  acc = __builtin_amdgcn_fdot2((f16x2)__builtin_shufflevector(w, w, 2, 3),
                               (f16x2)__builtin_shufflevector(x, x, 2, 3), acc, false);
  acc = __builtin_amdgcn_fdot2((f16x2)__builtin_shufflevector(w, w, 4, 5),
                               (f16x2)__builtin_shufflevector(x, x, 4, 5), acc, false);
  acc = __builtin_amdgcn_fdot2((f16x2)__builtin_shufflevector(w, w, 6, 7),
                               (f16x2)__builtin_shufflevector(x, x, 6, 7), acc, false);
#else
  #pragma unroll
  for (int e = 0; e < 8; ++e) acc += (float)w[e] * (float)x[e];
#endif
  return acc;
}
__device__ __forceinline__ float dot4(f16x4 w, f16x4 x, float acc) {
#if HAS_FDOT2
  acc = __builtin_amdgcn_fdot2((f16x2)__builtin_shufflevector(w, w, 0, 1),
                               (f16x2)__builtin_shufflevector(x, x, 0, 1), acc, false);
  acc = __builtin_amdgcn_fdot2((f16x2)__builtin_shufflevector(w, w, 2, 3),
                               (f16x2)__builtin_shufflevector(x, x, 2, 3), acc, false);
#else
  #pragma unroll
  for (int e = 0; e < 4; ++e) acc += (float)w[e] * (float)x[e];
#endif
  return acc;
}

#define S2SCAP 256   // absolute per-segment cap (binomial mean 128, sd 11)
#define NCAP 190     // rows cached in LDS; [NCAP,segT) via global fallback (normally empty)

// ---------------- Set2Set v9: + register-pinned hseg rows (P3) and blocks (P4) ----------
__global__ __launch_bounds__(512, 2) void s2s_kernel(
    const float* __restrict__ h, const f16* __restrict__ hf,
    const f16* __restrict__ Wcat,
    const float* __restrict__ lbih, const float* __restrict__ lbhh,
    const float* __restrict__ Wout, const float* __restrict__ bout,
    const int* __restrict__ segstarts, float* __restrict__ out) {
  __shared__ __align__(16) f16 hseg[NCAP * 84];   // 31920 B, row stride 84 f16 (b64-aligned)
  __shared__ __align__(16) f16 xcat[240];
  __shared__ float hhv[80];
  __shared__ float gatesv[292];
  __shared__ float earr[S2SCAP];
  __shared__ float red[4];
  __shared__ __align__(16) float rpart[19 * 80];
  const int t = threadIdx.x, b = blockIdx.x;
  const int wid = t >> 6, lane = t & 63;

  const int s0 = segstarts[b];
  int segT = segstarts[b + 1] - s0;
  if (segT > S2SCAP) segT = S2SCAP;
  const int c = segT < NCAP ? segT : NCAP;

  if (t < 240) xcat[t] = (f16)0.f;
  if (t < 80) hhv[t] = 0.f;
  if (t < S2SCAP) earr[t] = 0.f;   // pre-zero so P4 runs unguarded

  // stage hseg rows (f16, cols 0..75 data incl. zero pads 73..75; cols 76..83 zeroed);
  // rows [c, NCAP) fully zeroed so P4 needs no per-row guard (0*0 contributions)
  for (int r = wid; r < NCAP; r += 8) {
    if (lane < 21) {
      f16x4 v = {(f16)0.f, (f16)0.f, (f16)0.f, (f16)0.f};
      if (r < c && lane < 19)
        v = *(const f16x4*)(hf + (size_t)(s0 + r) * 96 + lane * 4);
      *(f16x4*)(hseg + r * 84 + lane * 4) = v;
    }
  }

  const bool isg = (t >= 220);
  const int g2 = t - 220;
  float bias = 0.f;
  if (isg) bias = lbih[g2] + lbhh[g2];
  // Folded LSTM weight row RESIDENT in registers (q==hh: Wcat[0..72]=wih_q+whh, [76..148]=wih_r)
  f16x8 wihF[19];
  {
    const f16* wr = Wcat + (size_t)(isg ? g2 : 0) * 232;
    #pragma unroll
    for (int v = 0; v < 19; ++v) wihF[v] = *(const f16x8*)(wr + v * 8);
  }
  const int nc = t / 10, fo = t - nc * 10;    // readout mapping (t<190)
  float creg = 0.f;                            // LSTM cell state (t<73)
  __syncthreads();                             // hseg staged & visible

  // ---- register pinning (loop-invariant LDS reads, clamped for inactive threads) ----
  f16x4 hrow[19];                              // P3: own hseg row (t<190; rows>=c are zero)
  {
    const f16* hp = hseg + (t < NCAP ? t : 0) * 84;
    #pragma unroll
    for (int k = 0; k < 19; ++k) hrow[k] = *(const f16x4*)(hp + k * 4);
  }
  f16x4 hb0[10], hb1[10];                      // P4: 10-node block at feature-octet fo
  {
    int ncc = (t < 190) ? nc : 0, foc = (t < 190) ? fo : 0;
    #pragma unroll
    for (int j = 0; j < 10; ++j) {
      const f16* hp = hseg + (ncc * 10 + j) * 84 + foc * 8;
      hb0[j] = *(const f16x4*)(hp);
      hb1[j] = *(const f16x4*)(hp + 4);
    }
  }

  for (int iter = 0; iter < 12; ++iter) {
    // ---- P1: LSTM gate matvec (292 threads), folded K=152, 4 accumulators ----
    if (isg) {
      float a0 = bias, a1 = 0.f, a2 = 0.f, a3 = 0.f;
      #pragma unroll
      for (int v = 0; v < 19; ++v) {
        f16x8 x = *(const f16x8*)(xcat + v * 8);
        int sel = v & 3;
        if (sel == 0) a0 = dot8(wihF[v], x, a0);
        else if (sel == 1) a1 = dot8(wihF[v], x, a1);
        else if (sel == 2) a2 = dot8(wihF[v], x, a2);
        else a3 = dot8(wihF[v], x, a3);
      }
      gatesv[g2] = (a0 + a1) + (a2 + a3);
    }
    __syncthreads();
    // ---- P2: LSTM elementwise update (t<73) ----
    if (t < 73) {
      float ig = 1.f / (1.f + __expf(-gatesv[t]));
      float fg = 1.f / (1.f + __expf(-gatesv[73 + t]));
      float gx = gatesv[146 + t];
      float gg = 2.f / (1.f + __expf(-2.f * gx)) - 1.f;
      float og = 1.f / (1.f + __expf(-gatesv[219 + t]));
      creg = fg * creg + ig * gg;
      float cth = 2.f / (1.f + __expf(-2.f * creg)) - 1.f;
      float hh = og * cth;
      hhv[t] = hh;
      xcat[t] = (f16)hh;        // q slot (doubles as hh via folded weights)
    }
    __syncthreads();
    // ---- P3: logits + exp + per-wave sums (t<192; hseg row from REGISTERS) ----
    if (wid < 3) {
      float a = 0.f;
      if (t < c) {
        float e0 = 0.f, e1 = 0.f;
        #pragma unroll
        for (int k = 0; k < 19; ++k) {
          f16x4 xk = *(const f16x4*)(xcat + k * 4);
          if (k & 1) e1 = dot4(hrow[k], xk, e1);
          else e0 = dot4(hrow[k], xk, e0);
        }
        a = __expf(fminf(e0 + e1, 80.f));  // logits bounded; no max-sub in fp32
        earr[t] = a;
      }
      float ws = wred_sum(a);
      if (lane == 0) red[wid] = ws;
    }
    // fallback logits for nodes >= NCAP (normally zero-trip)
    if (wid == 0) {
      float fa = 0.f;
      int n = NCAP + lane;
      if (n < segT) {
        const float* hr = h + (size_t)(s0 + n) * 96;
        float e = 0.f;
        for (int i = 0; i < 73; ++i) e += hr[i] * hhv[i];
        fa = __expf(fminf(e, 80.f));
        earr[n] = fa;
      }
      float ws2 = wred_sum(fa);
      if (lane == 0) red[3] = ws2;
    }
    __syncthreads();
    // ---- P4: weighted readout partials (hseg block from REGISTERS; earr zero-padded) ----
    if (t < 190) {
      float r0 = 0.f, r1 = 0.f, r2 = 0.f, r3 = 0.f, r4 = 0.f, r5 = 0.f, r6 = 0.f, r7 = 0.f;
      #pragma unroll
      for (int j = 0; j < 10; ++j) {
        float a = earr[nc * 10 + j];
        r0 += a * (float)hb0[j][0]; r1 += a * (float)hb0[j][1];
        r2 += a * (float)hb0[j][2]; r3 += a * (float)hb0[j][3];
        r4 += a * (float)hb1[j][0]; r5 += a * (float)hb1[j][1];
        r6 += a * (float)hb1[j][2]; r7 += a * (float)hb1[j][3];
      }
      if (nc == 18) {  // fallback nodes from global hf (normally zero-trip)
        for (int n = NCAP; n < segT; ++n) {
          float a = earr[n];
          const f16* hp = hf + (size_t)(s0 + n) * 96 + fo * 8;
          f16x4 v0 = *(const f16x4*)(hp);
          f16x4 v1 = *(const f16x4*)(hp + 4);
          r0 += a * (float)v0[0]; r1 += a * (float)v0[1];
          r2 += a * (float)v0[2]; r3 += a * (float)v0[3];
          r4 += a * (float)v1[0]; r5 += a * (float)v1[1];
          r6 += a * (float)v1[2]; r7 += a * (float)v1[3];
        }
      }
      f32x4 wa = {r0, r1, r2, r3}, wb = {r4, r5, r6, r7};
      *(f32x4*)(rpart + nc * 80 + fo * 8) = wa;
      *(f32x4*)(rpart + nc * 80 + fo * 8 + 4) = wb;
    }
    __syncthreads();
    // ---- P5: combine partials -> r into xcat (t<80) ----
    if (t < 80) {
      float S = red[0] + red[1] + red[2] + red[3];
      float invS = (S > 0.f) ? (1.f / S) : 0.f;
      float r = 0.f;
      #pragma unroll
      for (int ch = 0; ch < 19; ++ch) r += rpart[ch * 80 + t];
      if (t < 73) xcat[76 + t] = (f16)(r * invS);
    }
    __syncthreads();
  }
  // ---- output: out[b] = bout + hh . Wout ----
  if (t < 80) gatesv[t] = (t < 73) ? hhv[t] * Wout[t] : 0.f;
  __syncthreads();
  if (t == 0) {
    float a = bout[0];
    for (int i = 0; i < 73; ++i) a += gatesv[i];
    out[b] = a;
  }
}

// ---------------- workspace layout (bytes; ws_size = 256 MiB per harness fill) ----------------
#define OFF_H      0u          // float [8192][96]
#define OFF_G      3145728u    // f16 [2][8192][224] gate pre-activations
#define OFF_HF     17825792u   // f16 [8192][96]
#define OFF_AGGF   19398656u   // f16 [8192][96]
#define OFF_EHH    20971520u   // f16 [32768][80]
#define OFF_W2F    26214400u   // f16 [76][8192] fragment order, 16KB/kg (1.25 MB)
#define OFF_WIHT   27525120u   // f16 [224][96]
#define OFF_WHHT   27568128u   // f16 [224][96]
#define OFF_WCAT   27611136u   // f16 [292][232]
#define OFF_SEG    27746624u   // int [65]
#define OFF_CNT    27747072u   // int [8192]
#define OFF_BKT    27779840u   // int [8192][64]
#define OFF_M      29877248u   // f16 [32768][320] K-quarter partials (end ~50.8 MB)

extern "C" void kernel_launch(void* const* d_in, const int* in_sizes, int n_in,
                              void* d_out, int out_size, void* d_ws, size_t ws_size,
                              hipStream_t stream) {
  const float* nf   = (const float*)d_in[0];
  const float* ef   = (const float*)d_in[1];
  const float* W_in = (const float*)d_in[2];
  const float* b_in = (const float*)d_in[3];
  const float* W1   = (const float*)d_in[4];
  const float* b1   = (const float*)d_in[5];
  const float* W2   = (const float*)d_in[6];
  const float* b2   = (const float*)d_in[7];
  const float* gWih = (const float*)d_in[8];
  const float* gWhh = (const float*)d_in[9];
  const float* gbih = (const float*)d_in[10];
  const float* gbhh = (const float*)d_in[11];
  const float* lWih = (const float*)d_in[12];
  const float* lWhh = (const float*)d_in[13];
  const float* lbih = (const float*)d_in[14];
  const float* lbhh = (const float*)d_in[15];
  const float* Wout = (const float*)d_in[16];
  const float* bout = (const float*)d_in[17];
  const int* Esrc   = (const int*)d_in[18];
  const int* Etgt   = (const int*)d_in[19];
  const int* batch  = (const int*)d_in[20];

  char* ws = (char*)d_ws;
  float* h    = (float*)(ws + OFF_H);
  f16* G      = (f16*)(ws + OFF_G);
  f16* hf     = (f16*)(ws + OFF_HF);
  f16* aggf   = (f16*)(ws + OFF_AGGF);
  f16* ehh    = (f16*)(ws + OFF_EHH);
  f16* W2f    = (f16*)(ws + OFF_W2F);
  f16* WihT   = (f16*)(ws + OFF_WIHT);
  f16* WhhT   = (f16*)(ws + OFF_WHHT);
  f16* Wcat   = (f16*)(ws + OFF_WCAT);
  int* segst  = (int*)(ws + OFF_SEG);
  int* cnt    = (int*)(ws + OFF_CNT);
  int* bkt    = (int*)(ws + OFF_BKT);
  f16* m      = (f16*)(ws + OFF_M);

  hipMemsetAsync(cnt, 0, NN * sizeof(int), stream);
  prep_kernel<<<16306, 256, 0, stream>>>(nf, ef, W_in, b_in, W1, b1, W2, b2,
                                         gWih, gWhh, lWih, lWhh, batch, Etgt,
                                         h, hf, ehh, W2f, WihT, WhhT, Wcat,
                                         segst, cnt, bkt);
  for (int step = 0; step < 3; ++step) {
    vgemm_kernel<<<512, 256, 0, stream>>>(ehh, hf, W2f, Esrc, m);
    gather_kernel<<<768, 256, 0, stream>>>(m, cnt, bkt, aggf);
    grugemm_kernel<<<128, 256, 0, stream>>>(aggf, hf, WihT, WhhT, G);
    gate_kernel<<<2336, 256, 0, stream>>>(G, gbih, gbhh, h, hf);
  }
  s2s_kernel<<<64, 512, 0, stream>>>(h, hf, Wcat, lbih, lbhh, Wout, bout, segst,
                                     (float*)d_out);
}